// Round 4
// baseline (373.485 us; speedup 1.0000x reference)
//
#include <hip/hip_runtime.h>
#include <hip/hip_bf16.h>
#include <cstdint>
#include <cstddef>

// B=2, T=2048, D=1024, H=16, DH=64, CTX=2048.  M = B*T = 4096.

using bf16x8 = __attribute__((ext_vector_type(8))) __bf16;
using f32x4  = __attribute__((ext_vector_type(4))) float;

#define VMCNT(n) asm volatile("s_waitcnt vmcnt(" #n ")" ::: "memory")
#define LGKM0()  do { asm volatile("s_waitcnt lgkmcnt(0)" ::: "memory"); \
                      __builtin_amdgcn_sched_barrier(0); } while (0)
#define BARF()   do { asm volatile("" ::: "memory"); __builtin_amdgcn_s_barrier(); \
                      asm volatile("" ::: "memory"); } while (0)

__device__ __forceinline__ short f2b(float f) {
  uint32_t u = __builtin_bit_cast(uint32_t, f);
  uint32_t r = (u + 0x7FFFu + ((u >> 16) & 1u)) >> 16;
  return (short)r;
}
__device__ __forceinline__ float b2f(short s) {
  uint32_t u = ((uint32_t)(uint16_t)s) << 16;
  return __builtin_bit_cast(float, u);
}
// truncation pack of two f32 -> two bf16 in a u32 (P values in [0,1]; bias <0.4%)
__device__ __forceinline__ uint32_t pack2(float a, float b) {
  return (__builtin_bit_cast(uint32_t, a) >> 16) |
         (__builtin_bit_cast(uint32_t, b) & 0xFFFF0000u);
}

__device__ __forceinline__ void gload16(const short* g, short* l) {
  __builtin_amdgcn_global_load_lds(
      (const __attribute__((address_space(1))) void*)g,
      (__attribute__((address_space(3))) void*)l, 16, 0, 0);
}

// ---------------------------------------------------------------------------
// Staging, 64-col (128B) rows, XOR (row&7) swizzle applied on GLOBAL source,
// linear LDS dest (global_load_lds requirement).  Zero-bank-conflict verified.
// ---------------------------------------------------------------------------
template<int ROWS>  // 256 threads, ROWS/32 loads per thread
__device__ __forceinline__ void stage_swz(const short* __restrict__ g, int ldg,
                                          short* lds, int tid) {
#pragma unroll
  for (int jj = 0; jj < ROWS / 32; ++jj) {
    int row = jj * 32 + (tid >> 3);
    int seg = tid & 7;
    gload16(g + (size_t)row * ldg + ((seg ^ (row & 7)) << 3),
            lds + row * 64 + (seg << 3));
  }
}

// 512 threads, one 64-row round per call
__device__ __forceinline__ void stage_round512(const short* __restrict__ g, int ldg,
                                               short* lds, int tid, int rbase) {
  int row = rbase + (tid >> 3);
  int seg = tid & 7;
  gload16(g + (size_t)row * ldg + ((seg ^ (row & 7)) << 3),
          lds + row * 64 + (seg << 3));
}

__device__ __forceinline__ bf16x8 frag64(const short* lds, int row, int seg) {
  return *(const bf16x8*)(lds + row * 64 + ((seg ^ (row & 7)) << 3));
}

__device__ __forceinline__ f32x4 mma16(bf16x8 a, bf16x8 b, f32x4 c) {
  return __builtin_amdgcn_mfma_f32_16x16x32_bf16(a, b, c, 0, 0, 0);
}

// ---------------------------------------------------------------------------
// Fused weight conversion f32 -> bf16
// ---------------------------------------------------------------------------
__global__ void k_cvt_all(const float* __restrict__ wqkv, short* __restrict__ oqkv,
                          const float* __restrict__ wproj, short* __restrict__ oproj,
                          const float* __restrict__ wgate, short* __restrict__ ogate,
                          const float* __restrict__ wup, short* __restrict__ oup,
                          const float* __restrict__ wdown, short* __restrict__ odown) {
  int bid = blockIdx.x;
  const float* src;
  short* dst;
  int off;
  if (bid < 3072)       { src = wqkv;  dst = oqkv;  off = bid; }
  else if (bid < 4096)  { src = wproj; dst = oproj; off = bid - 3072; }
  else if (bid < 8192)  { src = wgate; dst = ogate; off = bid - 4096; }
  else if (bid < 12288) { src = wup;   dst = oup;   off = bid - 8192; }
  else                  { src = wdown; dst = odown; off = bid - 12288; }
  int i = off * 256 + threadIdx.x;
  float4 v = ((const float4*)src)[i];
  ((short4*)dst)[i] = make_short4(f2b(v.x), f2b(v.y), f2b(v.z), f2b(v.w));
}

// ---------------------------------------------------------------------------
// RMSNorm: one block (256 thr) per row of 1024 f32 -> bf16
// ---------------------------------------------------------------------------
__global__ void k_rms(const float* __restrict__ x, const float* __restrict__ w,
                      short* __restrict__ out) {
  int row = blockIdx.x;
  int tid = threadIdx.x;
  float4 v = *(const float4*)(x + (size_t)row * 1024 + tid * 4);
  float ss = v.x * v.x + v.y * v.y + v.z * v.z + v.w * v.w;
#pragma unroll
  for (int o = 1; o < 64; o <<= 1) ss += __shfl_xor(ss, o);
  __shared__ float sred[4];
  int wid = tid >> 6, lane = tid & 63;
  if (lane == 0) sred[wid] = ss;
  __syncthreads();
  float tot = sred[0] + sred[1] + sred[2] + sred[3];
  float r = rsqrtf(tot * (1.0f / 1024.0f) + 1e-6f);
  float4 wv = *(const float4*)(w + tid * 4);
  short4 o = make_short4(f2b(v.x * r * wv.x), f2b(v.y * r * wv.y),
                         f2b(v.z * r * wv.z), f2b(v.w * r * wv.w));
  *(short4*)(out + (size_t)row * 1024 + tid * 4) = o;
}

// ---------------------------------------------------------------------------
// Big GEMM: C = A[M,K] * W[N,K]^T, 256x256 tile, BK=64, 2-slot dbuf,
// 8 waves (2M x 4N, wave-tile 128x64), 4-phase schedule, counted vmcnt(8).
// MODE 1: outb = bf16(C)                 (gate)
// MODE 2: outb = bf16(silu(outb) * C)    (up)
// MODE 3: QKV epilogue
// ---------------------------------------------------------------------------
template<int MODE>
__global__ __launch_bounds__(512, 2) void k_gemm_big(
    const short* __restrict__ A, const short* __restrict__ Bw,
    int M, int N, int K, int gx,
    short* __restrict__ outb,
    short* __restrict__ q_b, short* __restrict__ k_b, short* __restrict__ vT_b,
    float* __restrict__ kc, float* __restrict__ vc) {
  __shared__ short As[2][256 * 64];  // 64 KB
  __shared__ short Bs[2][256 * 64];  // 64 KB
  int tid = threadIdx.x;
  int nwg = gridDim.x, bid = blockIdx.x;
  int swz = (bid & 7) * (nwg >> 3) + (bid >> 3);
  int bx = swz % gx, by = swz / gx;
  int m0 = by * 256, n0 = bx * 256;
  int w = tid >> 6, l = tid & 63;
  int wr = w >> 2, wc = w & 3;
  int lr = l & 15, lseg = l >> 4;
  f32x4 acc[2][2][4][2] = {};
  int nk = K >> 6;
  const short* Ab = A + (size_t)m0 * K;
  const short* Bb = Bw + (size_t)n0 * K;

  // prologue: A(0), B(0), A(1) fully staged (12 loads/thread)
#pragma unroll
  for (int r = 0; r < 4; ++r) stage_round512(Ab, K, &As[0][0], tid, r * 64);
#pragma unroll
  for (int r = 0; r < 4; ++r) stage_round512(Bb, K, &Bs[0][0], tid, r * 64);
#pragma unroll
  for (int r = 0; r < 4; ++r) stage_round512(Ab + 64, K, &As[1][0], tid, r * 64);
  VMCNT(0);
  BARF();

  bf16x8 ar[4][2], br[2][2];
#pragma unroll 1
  for (int u = 0; u < nk; ++u) {
    int s = u & 1;
    short* Asl = &As[s][0];
    short* Bsl = &Bs[s][0];
    const short* Ag2 = Ab + (u + 2) * 64;
    const short* Bg1 = Bb + (u + 1) * 64;

    // ---- phase 0: (ah0, bh0); stage B(u+1) -> Bs[s^1]
    if (u + 1 < nk) {
#pragma unroll
      for (int r = 0; r < 4; ++r) stage_round512(Bg1, K, &Bs[s ^ 1][0], tid, r * 64);
    }
    VMCNT(8);
    BARF();
#pragma unroll
    for (int i = 0; i < 4; ++i)
#pragma unroll
      for (int kk = 0; kk < 2; ++kk)
        ar[i][kk] = frag64(Asl, wr * 128 + i * 16 + lr, kk * 4 + lseg);
#pragma unroll
    for (int j = 0; j < 2; ++j)
#pragma unroll
      for (int kk = 0; kk < 2; ++kk)
        br[j][kk] = frag64(Bsl, wc * 64 + j * 16 + lr, kk * 4 + lseg);
    LGKM0();
    __builtin_amdgcn_s_setprio(1);
#pragma unroll
    for (int i = 0; i < 4; ++i)
#pragma unroll
      for (int j = 0; j < 2; ++j) {
        acc[0][0][i][j] = mma16(ar[i][0], br[j][0], acc[0][0][i][j]);
        acc[0][0][i][j] = mma16(ar[i][1], br[j][1], acc[0][0][i][j]);
      }
    __builtin_amdgcn_s_setprio(0);
    BARF();

    // ---- phase 1: (ah0, bh1); stage A(u+2) rounds 0,2 (freed by p0)
    if (u + 2 < nk) {
      stage_round512(Ag2, K, Asl, tid, 0);
      stage_round512(Ag2, K, Asl, tid, 128);
    }
#pragma unroll
    for (int j = 0; j < 2; ++j)
#pragma unroll
      for (int kk = 0; kk < 2; ++kk)
        br[j][kk] = frag64(Bsl, wc * 64 + 32 + j * 16 + lr, kk * 4 + lseg);
    LGKM0();
    __builtin_amdgcn_s_setprio(1);
#pragma unroll
    for (int i = 0; i < 4; ++i)
#pragma unroll
      for (int j = 0; j < 2; ++j) {
        acc[0][1][i][j] = mma16(ar[i][0], br[j][0], acc[0][1][i][j]);
        acc[0][1][i][j] = mma16(ar[i][1], br[j][1], acc[0][1][i][j]);
      }
    __builtin_amdgcn_s_setprio(0);

    // ---- phase 2: (ah1, bh0)
#pragma unroll
    for (int i = 0; i < 4; ++i)
#pragma unroll
      for (int kk = 0; kk < 2; ++kk)
        ar[i][kk] = frag64(Asl, wr * 128 + 64 + i * 16 + lr, kk * 4 + lseg);
#pragma unroll
    for (int j = 0; j < 2; ++j)
#pragma unroll
      for (int kk = 0; kk < 2; ++kk)
        br[j][kk] = frag64(Bsl, wc * 64 + j * 16 + lr, kk * 4 + lseg);
    LGKM0();
    __builtin_amdgcn_s_setprio(1);
#pragma unroll
    for (int i = 0; i < 4; ++i)
#pragma unroll
      for (int j = 0; j < 2; ++j) {
        acc[1][0][i][j] = mma16(ar[i][0], br[j][0], acc[1][0][i][j]);
        acc[1][0][i][j] = mma16(ar[i][1], br[j][1], acc[1][0][i][j]);
      }
    __builtin_amdgcn_s_setprio(0);
    BARF();

    // ---- phase 3: (ah1, bh1); stage A(u+2) rounds 1,3 (freed by p2)
    if (u + 2 < nk) {
      stage_round512(Ag2, K, Asl, tid, 64);
      stage_round512(Ag2, K, Asl, tid, 192);
    }
#pragma unroll
    for (int j = 0; j < 2; ++j)
#pragma unroll
      for (int kk = 0; kk < 2; ++kk)
        br[j][kk] = frag64(Bsl, wc * 64 + 32 + j * 16 + lr, kk * 4 + lseg);
    LGKM0();
    __builtin_amdgcn_s_setprio(1);
#pragma unroll
    for (int i = 0; i < 4; ++i)
#pragma unroll
      for (int j = 0; j < 2; ++j) {
        acc[1][1][i][j] = mma16(ar[i][0], br[j][0], acc[1][1][i][j]);
        acc[1][1][i][j] = mma16(ar[i][1], br[j][1], acc[1][1][i][j]);
      }
    __builtin_amdgcn_s_setprio(0);
    BARF();
  }

  // epilogue: C frag col = l&15, row = (l>>4)*4 + r
#pragma unroll
  for (int ah = 0; ah < 2; ++ah) {
#pragma unroll
    for (int bh = 0; bh < 2; ++bh) {
#pragma unroll
      for (int i = 0; i < 4; ++i) {
#pragma unroll
        for (int j = 0; j < 2; ++j) {
#pragma unroll
          for (int r = 0; r < 4; ++r) {
            int m = m0 + wr * 128 + ah * 64 + i * 16 + (l >> 4) * 4 + r;
            int n = n0 + wc * 64 + bh * 32 + j * 16 + lr;
            float f = acc[ah][bh][i][j][r];
            if (MODE == 1) {
              outb[(size_t)m * N + n] = f2b(f);
            } else if (MODE == 2) {
              float g = b2f(outb[(size_t)m * N + n]);
              float sg = g / (1.0f + __expf(-g));
              outb[(size_t)m * N + n] = f2b(sg * f);
            } else {
              int jj = n >> 10, hh = (n >> 6) & 15, dh = n & 63;
              int b_ = m >> 11, t = m & 2047;
              int bhh = b_ * 16 + hh;
              size_t idx = ((size_t)bhh * 2048 + t) * 64 + dh;
              if (jj == 0) {
                q_b[idx] = f2b(f);
              } else if (jj == 1) {
                k_b[idx] = f2b(f);
                kc[idx] = f;
              } else {
                vT_b[((size_t)bhh * 64 + dh) * 2048 + t] = f2b(f);
                vc[idx] = f;
              }
            }
          }
        }
      }
    }
  }
}

// ---------------------------------------------------------------------------
// Skinny GEMM: 128x64 tile, BK=64, ring-3, 4 waves (2M x 2N, wave 64x32).
// outf[m,n] = C + res[m,n]   (proj, down; N=1024 -> grid 32x16=512, 2 blk/CU)
// ---------------------------------------------------------------------------
__global__ __launch_bounds__(256, 2) void k_gemm_skinny(
    const short* __restrict__ A, const short* __restrict__ Bw,
    int M, int N, int K, int gx,
    const float* __restrict__ res, float* __restrict__ outf) {
  __shared__ short As[3][128 * 64];  // 48 KB
  __shared__ short Bs[3][64 * 64];   // 24 KB
  int tid = threadIdx.x;
  int nwg = gridDim.x, bid = blockIdx.x;
  int swz = (bid & 7) * (nwg >> 3) + (bid >> 3);
  int bx = swz % gx, by = swz / gx;
  int m0 = by * 128, n0 = bx * 64;
  int w = tid >> 6, l = tid & 63;
  int wr = w >> 1, wc = w & 1;
  int lr = l & 15, lseg = l >> 4;
  f32x4 acc[4][2] = {};
  int nk = K >> 6;
  const short* Ab = A + (size_t)m0 * K;
  const short* Bb = Bw + (size_t)n0 * K;

  stage_swz<128>(Ab, K, &As[0][0], tid);
  stage_swz<64>(Bb, K, &Bs[0][0], tid);
  stage_swz<128>(Ab + 64, K, &As[1][0], tid);
  stage_swz<64>(Bb + 64, K, &Bs[1][0], tid);

#pragma unroll 1
  for (int u = 0; u < nk; ++u) {
    VMCNT(6);   // tiles u+1, u+2 may stay in flight (6 loads/tile)
    BARF();
    if (u + 2 < nk) {
      int sl = (u + 2) % 3;
      stage_swz<128>(Ab + (u + 2) * 64, K, &As[sl][0], tid);
      stage_swz<64>(Bb + (u + 2) * 64, K, &Bs[sl][0], tid);
    }
    const short* Asl = &As[u % 3][0];
    const short* Bsl = &Bs[u % 3][0];
    bf16x8 ar[4][2], br[2][2];
#pragma unroll
    for (int i = 0; i < 4; ++i)
#pragma unroll
      for (int kk = 0; kk < 2; ++kk)
        ar[i][kk] = frag64(Asl, wr * 64 + i * 16 + lr, kk * 4 + lseg);
#pragma unroll
    for (int j = 0; j < 2; ++j)
#pragma unroll
      for (int kk = 0; kk < 2; ++kk)
        br[j][kk] = frag64(Bsl, wc * 32 + j * 16 + lr, kk * 4 + lseg);
    LGKM0();
    __builtin_amdgcn_s_setprio(1);
#pragma unroll
    for (int i = 0; i < 4; ++i)
#pragma unroll
      for (int j = 0; j < 2; ++j) {
        acc[i][j] = mma16(ar[i][0], br[j][0], acc[i][j]);
        acc[i][j] = mma16(ar[i][1], br[j][1], acc[i][j]);
      }
    __builtin_amdgcn_s_setprio(0);
  }

#pragma unroll
  for (int i = 0; i < 4; ++i) {
#pragma unroll
    for (int j = 0; j < 2; ++j) {
#pragma unroll
      for (int r = 0; r < 4; ++r) {
        int m = m0 + wr * 64 + i * 16 + (l >> 4) * 4 + r;
        int n = n0 + wc * 32 + j * 16 + lr;
        outf[(size_t)m * N + n] = acc[i][j][r] + res[(size_t)m * N + n];
      }
    }
  }
}

// ---------------------------------------------------------------------------
// Causal flash attention v2.
// Block = (qt, bh): 128 q rows, 4 waves x 32 q (two 16-col groups c=0,1).
// K/V double-buffered in LDS (one barrier + vmcnt(0) per tile, stage of
// tile kt+1 overlaps compute of tile kt).  Q frags held in registers.
// Swapped QK^T: S^T = mfma(K, Q); P staged per-wave in XOR-swizzled LDS.
// ---------------------------------------------------------------------------
__global__ __launch_bounds__(256, 3) void k_attn(const short* __restrict__ q_b,
                                                 const short* __restrict__ k_b,
                                                 const short* __restrict__ vT_b,
                                                 short* __restrict__ o_b) {
  __shared__ short Ks[2][64 * 64];   // 16 KB
  __shared__ short VTs[2][64 * 64];  // 16 KB
  __shared__ short Ps[4][32 * 64];   // 16 KB
  int tid = threadIdx.x;
  int w = tid >> 6, l = tid & 63;
  int lr = l & 15, g = l >> 4;
  int qt = blockIdx.x, bh = blockIdx.y;
  int q0 = qt * 128;
  int qb = q0 + w * 32;  // wave's first q row

  // Q fragments (B-operand layout: n = lr -> q row, k-elems = g*8 within kk*32)
  bf16x8 qf[2][2];
  const short* Qg = q_b + (size_t)bh * 2048 * 64;
#pragma unroll
  for (int c = 0; c < 2; ++c)
#pragma unroll
    for (int kk = 0; kk < 2; ++kk)
      qf[c][kk] = *(const bf16x8*)(Qg + (size_t)(qb + c * 16 + lr) * 64 + kk * 32 + g * 8);

  f32x4 acc[2][4] = {};
  float mrow[2] = {-INFINITY, -INFINITY};
  float dden[2] = {0.0f, 0.0f};
  int nt = 2 * qt + 2;
  const short* Kg = k_b + (size_t)bh * 2048 * 64;
  const short* Vg = vT_b + (size_t)bh * 64 * 2048;

  // prologue: stage tile 0
  stage_swz<64>(Kg, 64, &Ks[0][0], tid);
  stage_swz<64>(Vg, 2048, &VTs[0][0], tid);

#pragma unroll 1
  for (int kt = 0; kt < nt; ++kt) {
    int s = kt & 1;
    int kv0 = kt * 64;
    VMCNT(0);  // tile kt resident (its loads flew under tile kt-1's compute)
    BARF();    // all waves see it; all waves done reading slot s^1
    if (kt + 1 < nt) {
      stage_swz<64>(Kg + (size_t)(kv0 + 64) * 64, 64, &Ks[s ^ 1][0], tid);
      stage_swz<64>(Vg + kv0 + 64, 2048, &VTs[s ^ 1][0], tid);
    }
    if (kv0 > qb + 31) continue;  // tile entirely above diagonal for this wave

    const short* Ksl = &Ks[s][0];
    const short* Vsl = &VTs[s][0];
    short* pw = &Ps[w][0];
    bool band = (kv0 + 63 > qb);  // wave-uniform: diagonal band -> mask

#pragma unroll
    for (int c = 0; c < 2; ++c) {
      int qgc = qb + c * 16 + lr;
      // S^T = K * Q^T : 64 keys x 16 q
      f32x4 st[4];
#pragma unroll
      for (int i = 0; i < 4; ++i) {
        f32x4 z = {};
#pragma unroll
        for (int kk = 0; kk < 2; ++kk) {
          bf16x8 kf = frag64(Ksl, i * 16 + lr, kk * 4 + g);
          z = mma16(kf, qf[c][kk], z);
        }
        st[i] = z;
      }
      // online softmax in exp2 domain (scale*log2e folded in)
      const float SC = 0.125f * 1.44269504f;
      float p[16];
      float pm = -INFINITY;
#pragma unroll
      for (int i = 0; i < 4; ++i)
#pragma unroll
        for (int r = 0; r < 4; ++r) {
          float v = st[i][r] * SC;
          if (band) {
            int key = kv0 + i * 16 + g * 4 + r;
            if (key > qgc) v = -INFINITY;
          }
          p[i * 4 + r] = v;
          pm = fmaxf(pm, v);
        }
      pm = fmaxf(pm, __shfl_xor(pm, 16));
      pm = fmaxf(pm, __shfl_xor(pm, 32));
      float nm = fmaxf(mrow[c], pm);
      float corr = exp2f(mrow[c] - nm);
      float ds_ = 0.0f;
#pragma unroll
      for (int kx = 0; kx < 16; ++kx) {
        float pv = exp2f(p[kx] - nm);
        p[kx] = pv;
        ds_ += pv;
      }
      ds_ += __shfl_xor(ds_, 16);
      ds_ += __shfl_xor(ds_, 32);
      dden[c] = dden[c] * corr + ds_;
      mrow[c] = nm;
#pragma unroll
      for (int r = 0; r < 4; ++r) {
        float cr = __shfl(corr, g * 4 + r);
#pragma unroll
        for (int jf = 0; jf < 4; ++jf) acc[c][jf][r] *= cr;
      }
      // write P to swizzled LDS: row = c*16+lr (32 rows), 64 keys
      int prow = c * 16 + lr;
#pragma unroll
      for (int i = 0; i < 4; ++i) {
        uint2 pk;
        pk.x = pack2(p[i * 4 + 0], p[i * 4 + 1]);
        pk.y = pack2(p[i * 4 + 2], p[i * 4 + 3]);
        int seg = (i * 2 + (g >> 1)) ^ (prow & 7);
        *(uint2*)(pw + prow * 64 + seg * 8 + (g & 1) * 4) = pk;
      }
    }

    // PV: out[q, dh] += P[q, key] * V^T[dh, key]
#pragma unroll
    for (int kk = 0; kk < 2; ++kk) {
      bf16x8 vb[4];
#pragma unroll
      for (int jf = 0; jf < 4; ++jf)
        vb[jf] = frag64(Vsl, jf * 16 + lr, kk * 4 + g);
#pragma unroll
      for (int c = 0; c < 2; ++c) {
        int prow = c * 16 + lr;
        bf16x8 pa = *(const bf16x8*)(pw + prow * 64 + (((kk * 4 + g) ^ (prow & 7)) << 3));
#pragma unroll
        for (int jf = 0; jf < 4; ++jf)
          acc[c][jf] = mma16(pa, vb[jf], acc[c][jf]);
      }
    }
  }

  // epilogue: D col = dh-within = lr, row = q-within-16 = g*4 + r
  int hh = bh & 15, b_ = bh >> 4;
#pragma unroll
  for (int c = 0; c < 2; ++c) {
#pragma unroll
    for (int r = 0; r < 4; ++r) {
      float dq = __shfl(dden[c], g * 4 + r);
      float inv = 1.0f / dq;
      int mg = qb + c * 16 + g * 4 + r;
      size_t rowoff = ((size_t)b_ * 2048 + mg) * 1024 + hh * 64;
#pragma unroll
      for (int jf = 0; jf < 4; ++jf)
        o_b[rowoff + jf * 16 + lr] = f2b(acc[c][jf][r] * inv);
    }
  }
}

// ---------------------------------------------------------------------------
// Launch
// ---------------------------------------------------------------------------
extern "C" void kernel_launch(void* const* d_in, const int* in_sizes, int n_in,
                              void* d_out, int out_size, void* d_ws, size_t ws_size,
                              hipStream_t stream) {
  const float* x     = (const float*)d_in[0];
  const float* wn1   = (const float*)d_in[1];
  const float* wqkv  = (const float*)d_in[2];
  const float* wproj = (const float*)d_in[3];
  const float* wn2   = (const float*)d_in[4];
  const float* wgate = (const float*)d_in[5];
  const float* wup   = (const float*)d_in[6];
  const float* wdown = (const float*)d_in[7];
  float* out = (float*)d_out;
  char* ws = (char*)d_ws;

  short* wqkv_b  = (short*)(ws + 0);         //  6 MB
  short* wproj_b = (short*)(ws + 6291456);   //  2 MB
  short* wgate_b = (short*)(ws + 8388608);   //  8 MB
  short* wup_b   = (short*)(ws + 16777216);  //  8 MB
  short* wdown_b = (short*)(ws + 25165824);  //  8 MB
  short* h_b     = (short*)(ws + 33554432);  //  8 MB (h, then h2)
  short* q_b     = (short*)(ws + 41943040);  //  8 MB
  short* k_b     = (short*)(ws + 50331648);  //  8 MB
  short* vT_b    = (short*)(ws + 58720256);  //  8 MB
  short* ao_b    = (short*)(ws + 67108864);  //  8 MB
  short* act_b   = q_b;   // 32 MB alias over q/k/vT/ao (free after attention)
  float* x1 = out;
  float* kc = out + 4194304;
  float* vc = out + 8388608;

  k_cvt_all<<<16384, 256, 0, stream>>>(wqkv, wqkv_b, wproj, wproj_b,
                                       wgate, wgate_b, wup, wup_b, wdown, wdown_b);

  k_rms<<<4096, 256, 0, stream>>>(x, wn1, h_b);

  // qkv = h @ w_qkv^T  (grid 16x12 = 192 blocks)
  k_gemm_big<3><<<192, 512, 0, stream>>>(h_b, wqkv_b, 4096, 3072, 1024, 12,
                                         nullptr, q_b, k_b, vT_b, kc, vc);

  k_attn<<<dim3(16, 32), 256, 0, stream>>>(q_b, k_b, vT_b, ao_b);

  // x1 = x + attn @ w_proj^T  (grid 32x16 = 512 blocks)
  k_gemm_skinny<<<512, 256, 0, stream>>>(ao_b, wproj_b, 4096, 1024, 1024, 16,
                                         x, x1);

  k_rms<<<4096, 256, 0, stream>>>(x1, wn2, h_b);

  // gate = h2 @ w_gate^T (bf16)
  k_gemm_big<1><<<256, 512, 0, stream>>>(h_b, wgate_b, 4096, 4096, 1024, 16,
                                         act_b, nullptr, nullptr, nullptr, nullptr, nullptr);
  // act = silu(gate) * (h2 @ w_up^T)
  k_gemm_big<2><<<256, 512, 0, stream>>>(h_b, wup_b, 4096, 4096, 1024, 16,
                                         act_b, nullptr, nullptr, nullptr, nullptr, nullptr);
  // x_out = x1 + act @ w_down^T
  k_gemm_skinny<<<512, 256, 0, stream>>>(act_b, wdown_b, 4096, 1024, 4096, 16,
                                         x1, out);
}

// Round 5
// 354.592 us; speedup vs baseline: 1.0533x; 1.0533x over previous
//
#include <hip/hip_runtime.h>
#include <hip/hip_bf16.h>
#include <cstdint>
#include <cstddef>

// B=2, T=2048, D=1024, H=16, DH=64, CTX=2048.  M = B*T = 4096.

using bf16x8 = __attribute__((ext_vector_type(8))) __bf16;
using f32x4  = __attribute__((ext_vector_type(4))) float;

#define VMCNT(n) asm volatile("s_waitcnt vmcnt(" #n ")" ::: "memory")
#define LGKM0()  do { asm volatile("s_waitcnt lgkmcnt(0)" ::: "memory"); \
                      __builtin_amdgcn_sched_barrier(0); } while (0)
#define BARF()   do { asm volatile("" ::: "memory"); __builtin_amdgcn_s_barrier(); \
                      asm volatile("" ::: "memory"); } while (0)

__device__ __forceinline__ short f2b(float f) {
  uint32_t u = __builtin_bit_cast(uint32_t, f);
  uint32_t r = (u + 0x7FFFu + ((u >> 16) & 1u)) >> 16;
  return (short)r;
}
__device__ __forceinline__ float b2f(short s) {
  uint32_t u = ((uint32_t)(uint16_t)s) << 16;
  return __builtin_bit_cast(float, u);
}
// truncation pack of two f32 -> two bf16 in a u32 (P values in [0,1]; bias <0.4%)
__device__ __forceinline__ uint32_t pack2(float a, float b) {
  return (__builtin_bit_cast(uint32_t, a) >> 16) |
         (__builtin_bit_cast(uint32_t, b) & 0xFFFF0000u);
}

__device__ __forceinline__ void gload16(const short* g, short* l) {
  __builtin_amdgcn_global_load_lds(
      (const __attribute__((address_space(1))) void*)g,
      (__attribute__((address_space(3))) void*)l, 16, 0, 0);
}

// ---------------------------------------------------------------------------
// Staging, 64-col (128B) rows, XOR (row&7) swizzle applied on GLOBAL source,
// linear LDS dest (global_load_lds requirement).  Zero-bank-conflict verified.
// ---------------------------------------------------------------------------
template<int ROWS>  // 256 threads, ROWS/32 loads per thread
__device__ __forceinline__ void stage_swz(const short* __restrict__ g, int ldg,
                                          short* lds, int tid) {
#pragma unroll
  for (int jj = 0; jj < ROWS / 32; ++jj) {
    int row = jj * 32 + (tid >> 3);
    int seg = tid & 7;
    gload16(g + (size_t)row * ldg + ((seg ^ (row & 7)) << 3),
            lds + row * 64 + (seg << 3));
  }
}

// 512 threads, one 64-row round per call
__device__ __forceinline__ void stage_round512(const short* __restrict__ g, int ldg,
                                               short* lds, int tid, int rbase) {
  int row = rbase + (tid >> 3);
  int seg = tid & 7;
  gload16(g + (size_t)row * ldg + ((seg ^ (row & 7)) << 3),
          lds + row * 64 + (seg << 3));
}

__device__ __forceinline__ bf16x8 frag64(const short* lds, int row, int seg) {
  return *(const bf16x8*)(lds + row * 64 + ((seg ^ (row & 7)) << 3));
}

__device__ __forceinline__ f32x4 mma16(bf16x8 a, bf16x8 b, f32x4 c) {
  return __builtin_amdgcn_mfma_f32_16x16x32_bf16(a, b, c, 0, 0, 0);
}

// ---------------------------------------------------------------------------
// Fused weight conversion f32 -> bf16
// ---------------------------------------------------------------------------
__global__ void k_cvt_all(const float* __restrict__ wqkv, short* __restrict__ oqkv,
                          const float* __restrict__ wproj, short* __restrict__ oproj,
                          const float* __restrict__ wgate, short* __restrict__ ogate,
                          const float* __restrict__ wup, short* __restrict__ oup,
                          const float* __restrict__ wdown, short* __restrict__ odown) {
  int bid = blockIdx.x;
  const float* src;
  short* dst;
  int off;
  if (bid < 3072)       { src = wqkv;  dst = oqkv;  off = bid; }
  else if (bid < 4096)  { src = wproj; dst = oproj; off = bid - 3072; }
  else if (bid < 8192)  { src = wgate; dst = ogate; off = bid - 4096; }
  else if (bid < 12288) { src = wup;   dst = oup;   off = bid - 8192; }
  else                  { src = wdown; dst = odown; off = bid - 12288; }
  int i = off * 256 + threadIdx.x;
  float4 v = ((const float4*)src)[i];
  ((short4*)dst)[i] = make_short4(f2b(v.x), f2b(v.y), f2b(v.z), f2b(v.w));
}

// ---------------------------------------------------------------------------
// RMSNorm: one block (256 thr) per row of 1024 f32 -> bf16
// ---------------------------------------------------------------------------
__global__ void k_rms(const float* __restrict__ x, const float* __restrict__ w,
                      short* __restrict__ out) {
  int row = blockIdx.x;
  int tid = threadIdx.x;
  float4 v = *(const float4*)(x + (size_t)row * 1024 + tid * 4);
  float ss = v.x * v.x + v.y * v.y + v.z * v.z + v.w * v.w;
#pragma unroll
  for (int o = 1; o < 64; o <<= 1) ss += __shfl_xor(ss, o);
  __shared__ float sred[4];
  int wid = tid >> 6, lane = tid & 63;
  if (lane == 0) sred[wid] = ss;
  __syncthreads();
  float tot = sred[0] + sred[1] + sred[2] + sred[3];
  float r = rsqrtf(tot * (1.0f / 1024.0f) + 1e-6f);
  float4 wv = *(const float4*)(w + tid * 4);
  short4 o = make_short4(f2b(v.x * r * wv.x), f2b(v.y * r * wv.y),
                         f2b(v.z * r * wv.z), f2b(v.w * r * wv.w));
  *(short4*)(out + (size_t)row * 1024 + tid * 4) = o;
}

// ---------------------------------------------------------------------------
// Big GEMM: C = A[M,K] * W[N,K]^T, 256x256 tile, BK=64, 2-slot dbuf,
// 8 waves (2M x 4N, wave-tile 128x64), 4-phase schedule, counted vmcnt(8).
// MODE 1: outb = bf16(C)                 (gate)
// MODE 2: outb = bf16(silu(outb) * C)    (up)
// MODE 3: QKV epilogue
// ---------------------------------------------------------------------------
template<int MODE>
__global__ __launch_bounds__(512, 2) void k_gemm_big(
    const short* __restrict__ A, const short* __restrict__ Bw,
    int M, int N, int K, int gx,
    short* __restrict__ outb,
    short* __restrict__ q_b, short* __restrict__ k_b, short* __restrict__ vT_b,
    float* __restrict__ kc, float* __restrict__ vc) {
  __shared__ short As[2][256 * 64];  // 64 KB
  __shared__ short Bs[2][256 * 64];  // 64 KB
  int tid = threadIdx.x;
  int nwg = gridDim.x, bid = blockIdx.x;
  int swz = (bid & 7) * (nwg >> 3) + (bid >> 3);
  int bx = swz % gx, by = swz / gx;
  int m0 = by * 256, n0 = bx * 256;
  int w = tid >> 6, l = tid & 63;
  int wr = w >> 2, wc = w & 3;
  int lr = l & 15, lseg = l >> 4;
  f32x4 acc[2][2][4][2] = {};
  int nk = K >> 6;
  const short* Ab = A + (size_t)m0 * K;
  const short* Bb = Bw + (size_t)n0 * K;

  // prologue: A(0), B(0), A(1) fully staged (12 loads/thread)
#pragma unroll
  for (int r = 0; r < 4; ++r) stage_round512(Ab, K, &As[0][0], tid, r * 64);
#pragma unroll
  for (int r = 0; r < 4; ++r) stage_round512(Bb, K, &Bs[0][0], tid, r * 64);
#pragma unroll
  for (int r = 0; r < 4; ++r) stage_round512(Ab + 64, K, &As[1][0], tid, r * 64);
  VMCNT(0);
  BARF();

  bf16x8 ar[4][2], br[2][2];
#pragma unroll 1
  for (int u = 0; u < nk; ++u) {
    int s = u & 1;
    short* Asl = &As[s][0];
    short* Bsl = &Bs[s][0];
    const short* Ag2 = Ab + (u + 2) * 64;
    const short* Bg1 = Bb + (u + 1) * 64;

    // ---- phase 0: (ah0, bh0); stage B(u+1) -> Bs[s^1]
    if (u + 1 < nk) {
#pragma unroll
      for (int r = 0; r < 4; ++r) stage_round512(Bg1, K, &Bs[s ^ 1][0], tid, r * 64);
    }
    VMCNT(8);
    BARF();
#pragma unroll
    for (int i = 0; i < 4; ++i)
#pragma unroll
      for (int kk = 0; kk < 2; ++kk)
        ar[i][kk] = frag64(Asl, wr * 128 + i * 16 + lr, kk * 4 + lseg);
#pragma unroll
    for (int j = 0; j < 2; ++j)
#pragma unroll
      for (int kk = 0; kk < 2; ++kk)
        br[j][kk] = frag64(Bsl, wc * 64 + j * 16 + lr, kk * 4 + lseg);
    LGKM0();
    __builtin_amdgcn_s_setprio(1);
#pragma unroll
    for (int i = 0; i < 4; ++i)
#pragma unroll
      for (int j = 0; j < 2; ++j) {
        acc[0][0][i][j] = mma16(ar[i][0], br[j][0], acc[0][0][i][j]);
        acc[0][0][i][j] = mma16(ar[i][1], br[j][1], acc[0][0][i][j]);
      }
    __builtin_amdgcn_s_setprio(0);
    BARF();

    // ---- phase 1: (ah0, bh1); stage A(u+2) rounds 0,2 (freed by p0)
    if (u + 2 < nk) {
      stage_round512(Ag2, K, Asl, tid, 0);
      stage_round512(Ag2, K, Asl, tid, 128);
    }
#pragma unroll
    for (int j = 0; j < 2; ++j)
#pragma unroll
      for (int kk = 0; kk < 2; ++kk)
        br[j][kk] = frag64(Bsl, wc * 64 + 32 + j * 16 + lr, kk * 4 + lseg);
    LGKM0();
    __builtin_amdgcn_s_setprio(1);
#pragma unroll
    for (int i = 0; i < 4; ++i)
#pragma unroll
      for (int j = 0; j < 2; ++j) {
        acc[0][1][i][j] = mma16(ar[i][0], br[j][0], acc[0][1][i][j]);
        acc[0][1][i][j] = mma16(ar[i][1], br[j][1], acc[0][1][i][j]);
      }
    __builtin_amdgcn_s_setprio(0);

    // ---- phase 2: (ah1, bh0)
#pragma unroll
    for (int i = 0; i < 4; ++i)
#pragma unroll
      for (int kk = 0; kk < 2; ++kk)
        ar[i][kk] = frag64(Asl, wr * 128 + 64 + i * 16 + lr, kk * 4 + lseg);
#pragma unroll
    for (int j = 0; j < 2; ++j)
#pragma unroll
      for (int kk = 0; kk < 2; ++kk)
        br[j][kk] = frag64(Bsl, wc * 64 + j * 16 + lr, kk * 4 + lseg);
    LGKM0();
    __builtin_amdgcn_s_setprio(1);
#pragma unroll
    for (int i = 0; i < 4; ++i)
#pragma unroll
      for (int j = 0; j < 2; ++j) {
        acc[1][0][i][j] = mma16(ar[i][0], br[j][0], acc[1][0][i][j]);
        acc[1][0][i][j] = mma16(ar[i][1], br[j][1], acc[1][0][i][j]);
      }
    __builtin_amdgcn_s_setprio(0);
    BARF();

    // ---- phase 3: (ah1, bh1); stage A(u+2) rounds 1,3 (freed by p2)
    if (u + 2 < nk) {
      stage_round512(Ag2, K, Asl, tid, 64);
      stage_round512(Ag2, K, Asl, tid, 192);
    }
#pragma unroll
    for (int j = 0; j < 2; ++j)
#pragma unroll
      for (int kk = 0; kk < 2; ++kk)
        br[j][kk] = frag64(Bsl, wc * 64 + 32 + j * 16 + lr, kk * 4 + lseg);
    LGKM0();
    __builtin_amdgcn_s_setprio(1);
#pragma unroll
    for (int i = 0; i < 4; ++i)
#pragma unroll
      for (int j = 0; j < 2; ++j) {
        acc[1][1][i][j] = mma16(ar[i][0], br[j][0], acc[1][1][i][j]);
        acc[1][1][i][j] = mma16(ar[i][1], br[j][1], acc[1][1][i][j]);
      }
    __builtin_amdgcn_s_setprio(0);
    BARF();
  }

  // epilogue: C frag col = l&15, row = (l>>4)*4 + r
#pragma unroll
  for (int ah = 0; ah < 2; ++ah) {
#pragma unroll
    for (int bh = 0; bh < 2; ++bh) {
#pragma unroll
      for (int i = 0; i < 4; ++i) {
#pragma unroll
        for (int j = 0; j < 2; ++j) {
#pragma unroll
          for (int r = 0; r < 4; ++r) {
            int m = m0 + wr * 128 + ah * 64 + i * 16 + (l >> 4) * 4 + r;
            int n = n0 + wc * 64 + bh * 32 + j * 16 + lr;
            float f = acc[ah][bh][i][j][r];
            if (MODE == 1) {
              outb[(size_t)m * N + n] = f2b(f);
            } else if (MODE == 2) {
              float g = b2f(outb[(size_t)m * N + n]);
              float sg = g / (1.0f + __expf(-g));
              outb[(size_t)m * N + n] = f2b(sg * f);
            } else {
              int jj = n >> 10, hh = (n >> 6) & 15, dh = n & 63;
              int b_ = m >> 11, t = m & 2047;
              int bhh = b_ * 16 + hh;
              size_t idx = ((size_t)bhh * 2048 + t) * 64 + dh;
              if (jj == 0) {
                q_b[idx] = f2b(f);
              } else if (jj == 1) {
                k_b[idx] = f2b(f);
                kc[idx] = f;
              } else {
                vT_b[((size_t)bhh * 64 + dh) * 2048 + t] = f2b(f);
                vc[idx] = f;
              }
            }
          }
        }
      }
    }
  }
}

// ---------------------------------------------------------------------------
// Skinny GEMM: 128x64 tile, BK=64, ring-3, 4 waves (2M x 2N, wave 64x32).
// outf[m,n] = C + res[m,n]   (proj, down; N=1024 -> grid 32x16=512, 2 blk/CU)
// ---------------------------------------------------------------------------
__global__ __launch_bounds__(256, 2) void k_gemm_skinny(
    const short* __restrict__ A, const short* __restrict__ Bw,
    int M, int N, int K, int gx,
    const float* __restrict__ res, float* __restrict__ outf) {
  __shared__ short As[3][128 * 64];  // 48 KB
  __shared__ short Bs[3][64 * 64];   // 24 KB
  int tid = threadIdx.x;
  int nwg = gridDim.x, bid = blockIdx.x;
  int swz = (bid & 7) * (nwg >> 3) + (bid >> 3);
  int bx = swz % gx, by = swz / gx;
  int m0 = by * 128, n0 = bx * 64;
  int w = tid >> 6, l = tid & 63;
  int wr = w >> 1, wc = w & 1;
  int lr = l & 15, lseg = l >> 4;
  f32x4 acc[4][2] = {};
  int nk = K >> 6;
  const short* Ab = A + (size_t)m0 * K;
  const short* Bb = Bw + (size_t)n0 * K;

  stage_swz<128>(Ab, K, &As[0][0], tid);
  stage_swz<64>(Bb, K, &Bs[0][0], tid);
  stage_swz<128>(Ab + 64, K, &As[1][0], tid);
  stage_swz<64>(Bb + 64, K, &Bs[1][0], tid);

#pragma unroll 1
  for (int u = 0; u < nk; ++u) {
    VMCNT(6);   // tiles u+1, u+2 may stay in flight (6 loads/tile)
    BARF();
    if (u + 2 < nk) {
      int sl = (u + 2) % 3;
      stage_swz<128>(Ab + (u + 2) * 64, K, &As[sl][0], tid);
      stage_swz<64>(Bb + (u + 2) * 64, K, &Bs[sl][0], tid);
    }
    const short* Asl = &As[u % 3][0];
    const short* Bsl = &Bs[u % 3][0];
    bf16x8 ar[4][2], br[2][2];
#pragma unroll
    for (int i = 0; i < 4; ++i)
#pragma unroll
      for (int kk = 0; kk < 2; ++kk)
        ar[i][kk] = frag64(Asl, wr * 64 + i * 16 + lr, kk * 4 + lseg);
#pragma unroll
    for (int j = 0; j < 2; ++j)
#pragma unroll
      for (int kk = 0; kk < 2; ++kk)
        br[j][kk] = frag64(Bsl, wc * 32 + j * 16 + lr, kk * 4 + lseg);
    LGKM0();
    __builtin_amdgcn_s_setprio(1);
#pragma unroll
    for (int i = 0; i < 4; ++i)
#pragma unroll
      for (int j = 0; j < 2; ++j) {
        acc[i][j] = mma16(ar[i][0], br[j][0], acc[i][j]);
        acc[i][j] = mma16(ar[i][1], br[j][1], acc[i][j]);
      }
    __builtin_amdgcn_s_setprio(0);
  }

#pragma unroll
  for (int i = 0; i < 4; ++i) {
#pragma unroll
    for (int j = 0; j < 2; ++j) {
#pragma unroll
      for (int r = 0; r < 4; ++r) {
        int m = m0 + wr * 64 + i * 16 + (l >> 4) * 4 + r;
        int n = n0 + wc * 32 + j * 16 + lr;
        outf[(size_t)m * N + n] = acc[i][j][r] + res[(size_t)m * N + n];
      }
    }
  }
}

// ---------------------------------------------------------------------------
// Causal flash attention v3 — balanced diagonal pairing.
// Block = (i, bh), i in [0,16): processes q-tile pair (qlo=i, qhi=31-i),
// each 64 q rows (4 waves x 16 q per c-group; c=0 -> qlo, c=1 -> qhi).
// KV tiles 0..qhi staged ONCE (double-buffered); c=1 consumes all tiles,
// c=0 only kt <= qlo.  Work/block = 33 tile-computes, uniform across grid.
// Swapped QK^T: S^T = mfma(K, Q); P staged per-wave in XOR-swizzled LDS.
// ---------------------------------------------------------------------------
__global__ __launch_bounds__(256, 3) void k_attn(const short* __restrict__ q_b,
                                                 const short* __restrict__ k_b,
                                                 const short* __restrict__ vT_b,
                                                 short* __restrict__ o_b) {
  __shared__ short Ks[2][64 * 64];   // 16 KB
  __shared__ short VTs[2][64 * 64];  // 16 KB
  __shared__ short Ps[4][32 * 64];   // 16 KB
  int tid = threadIdx.x;
  int w = tid >> 6, l = tid & 63;
  int lr = l & 15, g = l >> 4;
  int ib = blockIdx.x, bh = blockIdx.y;
  int qlo = ib, qhi = 31 - ib;
  int qb0 = qlo * 64 + w * 16;  // wave q base, c=0
  int qb1 = qhi * 64 + w * 16;  // wave q base, c=1

  // Q fragments (B-operand: n-row = q = qb_c + lr, k-elems = kk*32 + g*8)
  bf16x8 qf[2][2];
  const short* Qg = q_b + (size_t)bh * 2048 * 64;
#pragma unroll
  for (int kk = 0; kk < 2; ++kk) {
    qf[0][kk] = *(const bf16x8*)(Qg + (size_t)(qb0 + lr) * 64 + kk * 32 + g * 8);
    qf[1][kk] = *(const bf16x8*)(Qg + (size_t)(qb1 + lr) * 64 + kk * 32 + g * 8);
  }

  f32x4 acc[2][4] = {};
  float mrow[2] = {-INFINITY, -INFINITY};
  float dden[2] = {0.0f, 0.0f};
  int nt = qhi + 1;
  const short* Kg = k_b + (size_t)bh * 2048 * 64;
  const short* Vg = vT_b + (size_t)bh * 64 * 2048;

  // prologue: stage tile 0
  stage_swz<64>(Kg, 64, &Ks[0][0], tid);
  stage_swz<64>(Vg, 2048, &VTs[0][0], tid);

#pragma unroll 1
  for (int kt = 0; kt < nt; ++kt) {
    int s = kt & 1;
    int kv0 = kt * 64;
    VMCNT(0);  // tile kt resident (its loads flew under tile kt-1's compute)
    BARF();    // all waves see it; all waves done reading slot s^1
    if (kt + 1 < nt) {
      stage_swz<64>(Kg + (size_t)(kv0 + 64) * 64, 64, &Ks[s ^ 1][0], tid);
      stage_swz<64>(Vg + kv0 + 64, 2048, &VTs[s ^ 1][0], tid);
    }

    const short* Ksl = &Ks[s][0];
    const short* Vsl = &VTs[s][0];
    short* pw = &Ps[w][0];

    // V fragments shared by both c-groups
    bf16x8 vb[2][4];
#pragma unroll
    for (int kk = 0; kk < 2; ++kk)
#pragma unroll
      for (int jf = 0; jf < 4; ++jf)
        vb[kk][jf] = frag64(Vsl, jf * 16 + lr, kk * 4 + g);

#pragma unroll
    for (int c = 0; c < 2; ++c) {
      if (c == 0 && kt > qlo) continue;           // block-uniform branch
      int qbc = (c == 0) ? qb0 : qb1;
      bool band = (kt == ((c == 0) ? qlo : qhi));  // diagonal tile -> mask
      int qgc = qbc + lr;

      // S^T = K * Q^T : 64 keys x 16 q
      f32x4 st[4];
#pragma unroll
      for (int i = 0; i < 4; ++i) {
        f32x4 z = {};
#pragma unroll
        for (int kk = 0; kk < 2; ++kk) {
          bf16x8 kf = frag64(Ksl, i * 16 + lr, kk * 4 + g);
          z = mma16(kf, qf[c][kk], z);
        }
        st[i] = z;
      }
      // online softmax in exp2 domain (scale*log2e folded in)
      const float SC = 0.125f * 1.44269504f;
      float p[16];
      float pm = -INFINITY;
#pragma unroll
      for (int i = 0; i < 4; ++i)
#pragma unroll
        for (int r = 0; r < 4; ++r) {
          float v = st[i][r] * SC;
          if (band) {
            int key = kv0 + i * 16 + g * 4 + r;
            if (key > qgc) v = -INFINITY;
          }
          p[i * 4 + r] = v;
          pm = fmaxf(pm, v);
        }
      pm = fmaxf(pm, __shfl_xor(pm, 16));
      pm = fmaxf(pm, __shfl_xor(pm, 32));
      float nm = fmaxf(mrow[c], pm);
      float corr = exp2f(mrow[c] - nm);
      float ds_ = 0.0f;
#pragma unroll
      for (int kx = 0; kx < 16; ++kx) {
        float pv = exp2f(p[kx] - nm);
        p[kx] = pv;
        ds_ += pv;
      }
      ds_ += __shfl_xor(ds_, 16);
      ds_ += __shfl_xor(ds_, 32);
      dden[c] = dden[c] * corr + ds_;
      mrow[c] = nm;
#pragma unroll
      for (int r = 0; r < 4; ++r) {
        float cr = __shfl(corr, g * 4 + r);
#pragma unroll
        for (int jf = 0; jf < 4; ++jf) acc[c][jf][r] *= cr;
      }
      // write P to swizzled LDS: buffer row = c*16 + lr
      int prow = c * 16 + lr;
#pragma unroll
      for (int i = 0; i < 4; ++i) {
        uint2 pk;
        pk.x = pack2(p[i * 4 + 0], p[i * 4 + 1]);
        pk.y = pack2(p[i * 4 + 2], p[i * 4 + 3]);
        int seg = (i * 2 + (g >> 1)) ^ (prow & 7);
        *(uint2*)(pw + prow * 64 + seg * 8 + (g & 1) * 4) = pk;
      }
      // PV: out[q, dh] += P[q, key] * V^T[dh, key]
#pragma unroll
      for (int kk = 0; kk < 2; ++kk) {
        bf16x8 pa = *(const bf16x8*)(pw + prow * 64 + (((kk * 4 + g) ^ (prow & 7)) << 3));
#pragma unroll
        for (int jf = 0; jf < 4; ++jf)
          acc[c][jf] = mma16(pa, vb[kk][jf], acc[c][jf]);
      }
    }
  }

  // epilogue: D col = dh-within = lr, row = q-within-16 = g*4 + r
  int hh = bh & 15, b_ = bh >> 4;
#pragma unroll
  for (int c = 0; c < 2; ++c) {
    int qbc = (c == 0) ? qb0 : qb1;
#pragma unroll
    for (int r = 0; r < 4; ++r) {
      float dq = __shfl(dden[c], g * 4 + r);
      float inv = 1.0f / dq;
      int mg = qbc + g * 4 + r;
      size_t rowoff = ((size_t)b_ * 2048 + mg) * 1024 + hh * 64;
#pragma unroll
      for (int jf = 0; jf < 4; ++jf)
        o_b[rowoff + jf * 16 + lr] = f2b(acc[c][jf][r] * inv);
    }
  }
}

// ---------------------------------------------------------------------------
// Launch
// ---------------------------------------------------------------------------
extern "C" void kernel_launch(void* const* d_in, const int* in_sizes, int n_in,
                              void* d_out, int out_size, void* d_ws, size_t ws_size,
                              hipStream_t stream) {
  const float* x     = (const float*)d_in[0];
  const float* wn1   = (const float*)d_in[1];
  const float* wqkv  = (const float*)d_in[2];
  const float* wproj = (const float*)d_in[3];
  const float* wn2   = (const float*)d_in[4];
  const float* wgate = (const float*)d_in[5];
  const float* wup   = (const float*)d_in[6];
  const float* wdown = (const float*)d_in[7];
  float* out = (float*)d_out;
  char* ws = (char*)d_ws;

  short* wqkv_b  = (short*)(ws + 0);         //  6 MB
  short* wproj_b = (short*)(ws + 6291456);   //  2 MB
  short* wgate_b = (short*)(ws + 8388608);   //  8 MB
  short* wup_b   = (short*)(ws + 16777216);  //  8 MB
  short* wdown_b = (short*)(ws + 25165824);  //  8 MB
  short* h_b     = (short*)(ws + 33554432);  //  8 MB (h, then h2)
  short* q_b     = (short*)(ws + 41943040);  //  8 MB
  short* k_b     = (short*)(ws + 50331648);  //  8 MB
  short* vT_b    = (short*)(ws + 58720256);  //  8 MB
  short* ao_b    = (short*)(ws + 67108864);  //  8 MB
  short* act_b   = q_b;   // 32 MB alias over q/k/vT/ao (free after attention)
  float* x1 = out;
  float* kc = out + 4194304;
  float* vc = out + 8388608;

  k_cvt_all<<<16384, 256, 0, stream>>>(wqkv, wqkv_b, wproj, wproj_b,
                                       wgate, wgate_b, wup, wup_b, wdown, wdown_b);

  k_rms<<<4096, 256, 0, stream>>>(x, wn1, h_b);

  // qkv = h @ w_qkv^T  (grid 16x12 = 192 blocks)
  k_gemm_big<3><<<192, 512, 0, stream>>>(h_b, wqkv_b, 4096, 3072, 1024, 12,
                                         nullptr, q_b, k_b, vT_b, kc, vc);

  k_attn<<<dim3(16, 32), 256, 0, stream>>>(q_b, k_b, vT_b, ao_b);

  // x1 = x + attn @ w_proj^T  (grid 32x16 = 512 blocks)
  k_gemm_skinny<<<512, 256, 0, stream>>>(ao_b, wproj_b, 4096, 1024, 1024, 16,
                                         x, x1);

  k_rms<<<4096, 256, 0, stream>>>(x1, wn2, h_b);

  // gate = h2 @ w_gate^T (bf16)
  k_gemm_big<1><<<256, 512, 0, stream>>>(h_b, wgate_b, 4096, 4096, 1024, 16,
                                         act_b, nullptr, nullptr, nullptr, nullptr, nullptr);
  // act = silu(gate) * (h2 @ w_up^T)
  k_gemm_big<2><<<256, 512, 0, stream>>>(h_b, wup_b, 4096, 4096, 1024, 16,
                                         act_b, nullptr, nullptr, nullptr, nullptr, nullptr);
  // x_out = x1 + act @ w_down^T
  k_gemm_skinny<<<512, 256, 0, stream>>>(act_b, wdown_b, 4096, 1024, 4096, 16,
                                         x1, out);
}

// Round 6
// 340.132 us; speedup vs baseline: 1.0981x; 1.0425x over previous
//
#include <hip/hip_runtime.h>
#include <hip/hip_bf16.h>
#include <cstdint>
#include <cstddef>

// B=2, T=2048, D=1024, H=16, DH=64, CTX=2048.  M = B*T = 4096.

using bf16x8 = __attribute__((ext_vector_type(8))) __bf16;
using f32x4  = __attribute__((ext_vector_type(4))) float;

#define VMCNT(n) asm volatile("s_waitcnt vmcnt(" #n ")" ::: "memory")
#define LGKM0()  do { asm volatile("s_waitcnt lgkmcnt(0)" ::: "memory"); \
                      __builtin_amdgcn_sched_barrier(0); } while (0)
#define BARF()   do { asm volatile("" ::: "memory"); __builtin_amdgcn_s_barrier(); \
                      asm volatile("" ::: "memory"); } while (0)

__device__ __forceinline__ short f2b(float f) {
  uint32_t u = __builtin_bit_cast(uint32_t, f);
  uint32_t r = (u + 0x7FFFu + ((u >> 16) & 1u)) >> 16;
  return (short)r;
}
__device__ __forceinline__ float b2f(short s) {
  uint32_t u = ((uint32_t)(uint16_t)s) << 16;
  return __builtin_bit_cast(float, u);
}
// truncation pack of two f32 -> two bf16 in a u32 (P values in [0,1]; bias <0.4%)
__device__ __forceinline__ uint32_t pack2(float a, float b) {
  return (__builtin_bit_cast(uint32_t, a) >> 16) |
         (__builtin_bit_cast(uint32_t, b) & 0xFFFF0000u);
}

__device__ __forceinline__ void gload16(const short* g, short* l) {
  __builtin_amdgcn_global_load_lds(
      (const __attribute__((address_space(1))) void*)g,
      (__attribute__((address_space(3))) void*)l, 16, 0, 0);
}

// ---------------------------------------------------------------------------
// Staging, 64-col (128B) rows, XOR (row&7) swizzle applied on GLOBAL source,
// linear LDS dest (global_load_lds requirement).  Zero-bank-conflict verified.
// ---------------------------------------------------------------------------
template<int ROWS>  // 256 threads, ROWS/32 loads per thread
__device__ __forceinline__ void stage_swz(const short* __restrict__ g, int ldg,
                                          short* lds, int tid) {
#pragma unroll
  for (int jj = 0; jj < ROWS / 32; ++jj) {
    int row = jj * 32 + (tid >> 3);
    int seg = tid & 7;
    gload16(g + (size_t)row * ldg + ((seg ^ (row & 7)) << 3),
            lds + row * 64 + (seg << 3));
  }
}

// 512 threads, one 64-row round per call
__device__ __forceinline__ void stage_round512(const short* __restrict__ g, int ldg,
                                               short* lds, int tid, int rbase) {
  int row = rbase + (tid >> 3);
  int seg = tid & 7;
  gload16(g + (size_t)row * ldg + ((seg ^ (row & 7)) << 3),
          lds + row * 64 + (seg << 3));
}

__device__ __forceinline__ bf16x8 frag64(const short* lds, int row, int seg) {
  return *(const bf16x8*)(lds + row * 64 + ((seg ^ (row & 7)) << 3));
}

__device__ __forceinline__ f32x4 mma16(bf16x8 a, bf16x8 b, f32x4 c) {
  return __builtin_amdgcn_mfma_f32_16x16x32_bf16(a, b, c, 0, 0, 0);
}

// ---------------------------------------------------------------------------
// Fused weight conversion f32 -> bf16
// ---------------------------------------------------------------------------
__global__ void k_cvt_all(const float* __restrict__ wqkv, short* __restrict__ oqkv,
                          const float* __restrict__ wproj, short* __restrict__ oproj,
                          const float* __restrict__ wgate, short* __restrict__ ogate,
                          const float* __restrict__ wup, short* __restrict__ oup,
                          const float* __restrict__ wdown, short* __restrict__ odown) {
  int bid = blockIdx.x;
  const float* src;
  short* dst;
  int off;
  if (bid < 3072)       { src = wqkv;  dst = oqkv;  off = bid; }
  else if (bid < 4096)  { src = wproj; dst = oproj; off = bid - 3072; }
  else if (bid < 8192)  { src = wgate; dst = ogate; off = bid - 4096; }
  else if (bid < 12288) { src = wup;   dst = oup;   off = bid - 8192; }
  else                  { src = wdown; dst = odown; off = bid - 12288; }
  int i = off * 256 + threadIdx.x;
  float4 v = ((const float4*)src)[i];
  ((short4*)dst)[i] = make_short4(f2b(v.x), f2b(v.y), f2b(v.z), f2b(v.w));
}

// ---------------------------------------------------------------------------
// RMSNorm: one block (256 thr) per row of 1024 f32 -> bf16
// ---------------------------------------------------------------------------
__global__ void k_rms(const float* __restrict__ x, const float* __restrict__ w,
                      short* __restrict__ out) {
  int row = blockIdx.x;
  int tid = threadIdx.x;
  float4 v = *(const float4*)(x + (size_t)row * 1024 + tid * 4);
  float ss = v.x * v.x + v.y * v.y + v.z * v.z + v.w * v.w;
#pragma unroll
  for (int o = 1; o < 64; o <<= 1) ss += __shfl_xor(ss, o);
  __shared__ float sred[4];
  int wid = tid >> 6, lane = tid & 63;
  if (lane == 0) sred[wid] = ss;
  __syncthreads();
  float tot = sred[0] + sred[1] + sred[2] + sred[3];
  float r = rsqrtf(tot * (1.0f / 1024.0f) + 1e-6f);
  float4 wv = *(const float4*)(w + tid * 4);
  short4 o = make_short4(f2b(v.x * r * wv.x), f2b(v.y * r * wv.y),
                         f2b(v.z * r * wv.z), f2b(v.w * r * wv.w));
  *(short4*)(out + (size_t)row * 1024 + tid * 4) = o;
}

// ---------------------------------------------------------------------------
// Big GEMM: C = A[M,K] * W[N,K]^T, 256x256 tile, BK=64, 2-slot dbuf,
// 8 waves (2M x 4N, wave-tile 128x64), 4-phase schedule, counted vmcnt(8).
// MODE 1: outb = bf16(C)                 (gate)
// MODE 2: outb = bf16(silu(outb) * C)    (up)
// MODE 3: QKV epilogue
// ---------------------------------------------------------------------------
template<int MODE>
__global__ __launch_bounds__(512, 2) void k_gemm_big(
    const short* __restrict__ A, const short* __restrict__ Bw,
    int M, int N, int K, int gx,
    short* __restrict__ outb,
    short* __restrict__ q_b, short* __restrict__ k_b, short* __restrict__ vT_b,
    float* __restrict__ kc, float* __restrict__ vc) {
  __shared__ short As[2][256 * 64];  // 64 KB
  __shared__ short Bs[2][256 * 64];  // 64 KB
  int tid = threadIdx.x;
  int nwg = gridDim.x, bid = blockIdx.x;
  int swz = (bid & 7) * (nwg >> 3) + (bid >> 3);
  int bx = swz % gx, by = swz / gx;
  int m0 = by * 256, n0 = bx * 256;
  int w = tid >> 6, l = tid & 63;
  int wr = w >> 2, wc = w & 3;
  int lr = l & 15, lseg = l >> 4;
  f32x4 acc[2][2][4][2] = {};
  int nk = K >> 6;
  const short* Ab = A + (size_t)m0 * K;
  const short* Bb = Bw + (size_t)n0 * K;

  // prologue: A(0), B(0), A(1) fully staged (12 loads/thread)
#pragma unroll
  for (int r = 0; r < 4; ++r) stage_round512(Ab, K, &As[0][0], tid, r * 64);
#pragma unroll
  for (int r = 0; r < 4; ++r) stage_round512(Bb, K, &Bs[0][0], tid, r * 64);
#pragma unroll
  for (int r = 0; r < 4; ++r) stage_round512(Ab + 64, K, &As[1][0], tid, r * 64);
  VMCNT(0);
  BARF();

  bf16x8 ar[4][2], br[2][2];
#pragma unroll 1
  for (int u = 0; u < nk; ++u) {
    int s = u & 1;
    short* Asl = &As[s][0];
    short* Bsl = &Bs[s][0];
    const short* Ag2 = Ab + (u + 2) * 64;
    const short* Bg1 = Bb + (u + 1) * 64;

    // ---- phase 0: (ah0, bh0); stage B(u+1) -> Bs[s^1]
    if (u + 1 < nk) {
#pragma unroll
      for (int r = 0; r < 4; ++r) stage_round512(Bg1, K, &Bs[s ^ 1][0], tid, r * 64);
    }
    VMCNT(8);
    BARF();
#pragma unroll
    for (int i = 0; i < 4; ++i)
#pragma unroll
      for (int kk = 0; kk < 2; ++kk)
        ar[i][kk] = frag64(Asl, wr * 128 + i * 16 + lr, kk * 4 + lseg);
#pragma unroll
    for (int j = 0; j < 2; ++j)
#pragma unroll
      for (int kk = 0; kk < 2; ++kk)
        br[j][kk] = frag64(Bsl, wc * 64 + j * 16 + lr, kk * 4 + lseg);
    LGKM0();
    __builtin_amdgcn_s_setprio(1);
#pragma unroll
    for (int i = 0; i < 4; ++i)
#pragma unroll
      for (int j = 0; j < 2; ++j) {
        acc[0][0][i][j] = mma16(ar[i][0], br[j][0], acc[0][0][i][j]);
        acc[0][0][i][j] = mma16(ar[i][1], br[j][1], acc[0][0][i][j]);
      }
    __builtin_amdgcn_s_setprio(0);
    BARF();

    // ---- phase 1: (ah0, bh1); stage A(u+2) rounds 0,2 (freed by p0)
    if (u + 2 < nk) {
      stage_round512(Ag2, K, Asl, tid, 0);
      stage_round512(Ag2, K, Asl, tid, 128);
    }
#pragma unroll
    for (int j = 0; j < 2; ++j)
#pragma unroll
      for (int kk = 0; kk < 2; ++kk)
        br[j][kk] = frag64(Bsl, wc * 64 + 32 + j * 16 + lr, kk * 4 + lseg);
    LGKM0();
    __builtin_amdgcn_s_setprio(1);
#pragma unroll
    for (int i = 0; i < 4; ++i)
#pragma unroll
      for (int j = 0; j < 2; ++j) {
        acc[0][1][i][j] = mma16(ar[i][0], br[j][0], acc[0][1][i][j]);
        acc[0][1][i][j] = mma16(ar[i][1], br[j][1], acc[0][1][i][j]);
      }
    __builtin_amdgcn_s_setprio(0);

    // ---- phase 2: (ah1, bh0)
#pragma unroll
    for (int i = 0; i < 4; ++i)
#pragma unroll
      for (int kk = 0; kk < 2; ++kk)
        ar[i][kk] = frag64(Asl, wr * 128 + 64 + i * 16 + lr, kk * 4 + lseg);
#pragma unroll
    for (int j = 0; j < 2; ++j)
#pragma unroll
      for (int kk = 0; kk < 2; ++kk)
        br[j][kk] = frag64(Bsl, wc * 64 + j * 16 + lr, kk * 4 + lseg);
    LGKM0();
    __builtin_amdgcn_s_setprio(1);
#pragma unroll
    for (int i = 0; i < 4; ++i)
#pragma unroll
      for (int j = 0; j < 2; ++j) {
        acc[1][0][i][j] = mma16(ar[i][0], br[j][0], acc[1][0][i][j]);
        acc[1][0][i][j] = mma16(ar[i][1], br[j][1], acc[1][0][i][j]);
      }
    __builtin_amdgcn_s_setprio(0);
    BARF();

    // ---- phase 3: (ah1, bh1); stage A(u+2) rounds 1,3 (freed by p2)
    if (u + 2 < nk) {
      stage_round512(Ag2, K, Asl, tid, 64);
      stage_round512(Ag2, K, Asl, tid, 192);
    }
#pragma unroll
    for (int j = 0; j < 2; ++j)
#pragma unroll
      for (int kk = 0; kk < 2; ++kk)
        br[j][kk] = frag64(Bsl, wc * 64 + 32 + j * 16 + lr, kk * 4 + lseg);
    LGKM0();
    __builtin_amdgcn_s_setprio(1);
#pragma unroll
    for (int i = 0; i < 4; ++i)
#pragma unroll
      for (int j = 0; j < 2; ++j) {
        acc[1][1][i][j] = mma16(ar[i][0], br[j][0], acc[1][1][i][j]);
        acc[1][1][i][j] = mma16(ar[i][1], br[j][1], acc[1][1][i][j]);
      }
    __builtin_amdgcn_s_setprio(0);
    BARF();
  }

  // epilogue: C frag col = l&15, row = (l>>4)*4 + r
#pragma unroll
  for (int ah = 0; ah < 2; ++ah) {
#pragma unroll
    for (int bh = 0; bh < 2; ++bh) {
#pragma unroll
      for (int i = 0; i < 4; ++i) {
#pragma unroll
        for (int j = 0; j < 2; ++j) {
#pragma unroll
          for (int r = 0; r < 4; ++r) {
            int m = m0 + wr * 128 + ah * 64 + i * 16 + (l >> 4) * 4 + r;
            int n = n0 + wc * 64 + bh * 32 + j * 16 + lr;
            float f = acc[ah][bh][i][j][r];
            if (MODE == 1) {
              outb[(size_t)m * N + n] = f2b(f);
            } else if (MODE == 2) {
              float g = b2f(outb[(size_t)m * N + n]);
              float sg = g / (1.0f + __expf(-g));
              outb[(size_t)m * N + n] = f2b(sg * f);
            } else {
              int jj = n >> 10, hh = (n >> 6) & 15, dh = n & 63;
              int b_ = m >> 11, t = m & 2047;
              int bhh = b_ * 16 + hh;
              size_t idx = ((size_t)bhh * 2048 + t) * 64 + dh;
              if (jj == 0) {
                q_b[idx] = f2b(f);
              } else if (jj == 1) {
                k_b[idx] = f2b(f);
                kc[idx] = f;
              } else {
                vT_b[((size_t)bhh * 64 + dh) * 2048 + t] = f2b(f);
                vc[idx] = f;
              }
            }
          }
        }
      }
    }
  }
}

// ---------------------------------------------------------------------------
// Skinny GEMM: 128x64 tile, BK=64, ring-3, 4 waves (2M x 2N, wave 64x32).
// outf[m,n] = C + res[m,n]   (proj, down; N=1024 -> grid 32x16=512, 2 blk/CU)
// ---------------------------------------------------------------------------
__global__ __launch_bounds__(256, 2) void k_gemm_skinny(
    const short* __restrict__ A, const short* __restrict__ Bw,
    int M, int N, int K, int gx,
    const float* __restrict__ res, float* __restrict__ outf) {
  __shared__ short As[3][128 * 64];  // 48 KB
  __shared__ short Bs[3][64 * 64];   // 24 KB
  int tid = threadIdx.x;
  int nwg = gridDim.x, bid = blockIdx.x;
  int swz = (bid & 7) * (nwg >> 3) + (bid >> 3);
  int bx = swz % gx, by = swz / gx;
  int m0 = by * 128, n0 = bx * 64;
  int w = tid >> 6, l = tid & 63;
  int wr = w >> 1, wc = w & 1;
  int lr = l & 15, lseg = l >> 4;
  f32x4 acc[4][2] = {};
  int nk = K >> 6;
  const short* Ab = A + (size_t)m0 * K;
  const short* Bb = Bw + (size_t)n0 * K;

  stage_swz<128>(Ab, K, &As[0][0], tid);
  stage_swz<64>(Bb, K, &Bs[0][0], tid);
  stage_swz<128>(Ab + 64, K, &As[1][0], tid);
  stage_swz<64>(Bb + 64, K, &Bs[1][0], tid);

#pragma unroll 1
  for (int u = 0; u < nk; ++u) {
    VMCNT(6);   // tiles u+1, u+2 may stay in flight (6 loads/tile)
    BARF();
    if (u + 2 < nk) {
      int sl = (u + 2) % 3;
      stage_swz<128>(Ab + (u + 2) * 64, K, &As[sl][0], tid);
      stage_swz<64>(Bb + (u + 2) * 64, K, &Bs[sl][0], tid);
    }
    const short* Asl = &As[u % 3][0];
    const short* Bsl = &Bs[u % 3][0];
    bf16x8 ar[4][2], br[2][2];
#pragma unroll
    for (int i = 0; i < 4; ++i)
#pragma unroll
      for (int kk = 0; kk < 2; ++kk)
        ar[i][kk] = frag64(Asl, wr * 64 + i * 16 + lr, kk * 4 + lseg);
#pragma unroll
    for (int j = 0; j < 2; ++j)
#pragma unroll
      for (int kk = 0; kk < 2; ++kk)
        br[j][kk] = frag64(Bsl, wc * 32 + j * 16 + lr, kk * 4 + lseg);
    LGKM0();
    __builtin_amdgcn_s_setprio(1);
#pragma unroll
    for (int i = 0; i < 4; ++i)
#pragma unroll
      for (int j = 0; j < 2; ++j) {
        acc[i][j] = mma16(ar[i][0], br[j][0], acc[i][j]);
        acc[i][j] = mma16(ar[i][1], br[j][1], acc[i][j]);
      }
    __builtin_amdgcn_s_setprio(0);
  }

#pragma unroll
  for (int i = 0; i < 4; ++i) {
#pragma unroll
    for (int j = 0; j < 2; ++j) {
#pragma unroll
      for (int r = 0; r < 4; ++r) {
        int m = m0 + wr * 64 + i * 16 + (l >> 4) * 4 + r;
        int n = n0 + wc * 32 + j * 16 + lr;
        outf[(size_t)m * N + n] = acc[i][j][r] + res[(size_t)m * N + n];
      }
    }
  }
}

// ---------------------------------------------------------------------------
// Causal flash attention v4 — balanced pairing + ring-3 counted-vmcnt
// prefetch + interleaved c-groups via phase-split loops.
// Block = (i, bh), i in [0,16): q-tile pair (qlo=i, qhi=31-i), 64 rows each.
// Phase A (kt <= qlo): both c-groups per tile (tile_step<2>);
// Phase B (qlo < kt <= qhi): only the high tile (tile_step<1>).
// Work/block = 33 tile-computes, uniform.  KV staged once per block,
// ring-3 LDS, prefetch distance 2, vmcnt(4) so loads have a full
// iteration to land.  K/V fragments hoisted and shared across c-groups.
// ---------------------------------------------------------------------------
template<int NC>
__device__ __forceinline__ void attn_tile(
    const short* __restrict__ Ksl, const short* __restrict__ Vsl,
    short* __restrict__ pw,
    const bf16x8 (&qf)[2][2], f32x4 (&acc)[2][4],
    float (&mrow)[2], float (&dden)[2],
    int kv0, int qb0, int qb1, bool band0, bool band1,
    int lr, int g) {
  // hoisted K and V fragments (shared across c-groups)
  bf16x8 kf[4][2], vb[2][4];
#pragma unroll
  for (int i = 0; i < 4; ++i)
#pragma unroll
    for (int kk = 0; kk < 2; ++kk)
      kf[i][kk] = frag64(Ksl, i * 16 + lr, kk * 4 + g);
#pragma unroll
  for (int kk = 0; kk < 2; ++kk)
#pragma unroll
    for (int jf = 0; jf < 4; ++jf)
      vb[kk][jf] = frag64(Vsl, jf * 16 + lr, kk * 4 + g);

  // QK^T for all active c-groups (independent MFMAs -> ILP)
  f32x4 st[NC][4];
#pragma unroll
  for (int c = 0; c < NC; ++c) {
    int cc = (NC == 2) ? c : 1;
#pragma unroll
    for (int i = 0; i < 4; ++i) {
      f32x4 z = {};
      z = mma16(kf[i][0], qf[cc][0], z);
      z = mma16(kf[i][1], qf[cc][1], z);
      st[c][i] = z;
    }
  }

  // online softmax in exp2 domain, both chains interleaved
  const float SC = 0.125f * 1.44269504f;
  float p[NC][16], pm[NC], corr[NC];
#pragma unroll
  for (int c = 0; c < NC; ++c) {
    int cc = (NC == 2) ? c : 1;
    bool band = (cc == 0) ? band0 : band1;
    int qgc = ((cc == 0) ? qb0 : qb1) + lr;
    float m_ = -INFINITY;
#pragma unroll
    for (int i = 0; i < 4; ++i)
#pragma unroll
      for (int r = 0; r < 4; ++r) {
        float v = st[c][i][r] * SC;
        if (band) {
          int key = kv0 + i * 16 + g * 4 + r;
          if (key > qgc) v = -INFINITY;
        }
        p[c][i * 4 + r] = v;
        m_ = fmaxf(m_, v);
      }
    pm[c] = m_;
  }
#pragma unroll
  for (int c = 0; c < NC; ++c) pm[c] = fmaxf(pm[c], __shfl_xor(pm[c], 16));
#pragma unroll
  for (int c = 0; c < NC; ++c) pm[c] = fmaxf(pm[c], __shfl_xor(pm[c], 32));
  float dsum[NC];
#pragma unroll
  for (int c = 0; c < NC; ++c) {
    int cc = (NC == 2) ? c : 1;
    float nm = fmaxf(mrow[cc], pm[c]);
    corr[c] = exp2f(mrow[cc] - nm);
    mrow[cc] = nm;
    float ds_ = 0.0f;
#pragma unroll
    for (int kx = 0; kx < 16; ++kx) {
      float pv = exp2f(p[c][kx] - nm);
      p[c][kx] = pv;
      ds_ += pv;
    }
    dsum[c] = ds_;
  }
#pragma unroll
  for (int c = 0; c < NC; ++c) dsum[c] += __shfl_xor(dsum[c], 16);
#pragma unroll
  for (int c = 0; c < NC; ++c) dsum[c] += __shfl_xor(dsum[c], 32);
#pragma unroll
  for (int c = 0; c < NC; ++c) {
    int cc = (NC == 2) ? c : 1;
    dden[cc] = dden[cc] * corr[c] + dsum[c];
  }

  // rescale acc + write P to swizzled per-wave LDS
#pragma unroll
  for (int c = 0; c < NC; ++c) {
    int cc = (NC == 2) ? c : 1;
#pragma unroll
    for (int r = 0; r < 4; ++r) {
      float cr = __shfl(corr[c], g * 4 + r);
#pragma unroll
      for (int jf = 0; jf < 4; ++jf) acc[cc][jf][r] *= cr;
    }
    int prow = cc * 16 + lr;
#pragma unroll
    for (int i = 0; i < 4; ++i) {
      uint2 pk;
      pk.x = pack2(p[c][i * 4 + 0], p[c][i * 4 + 1]);
      pk.y = pack2(p[c][i * 4 + 2], p[c][i * 4 + 3]);
      int seg = (i * 2 + (g >> 1)) ^ (prow & 7);
      *(uint2*)(pw + prow * 64 + seg * 8 + (g & 1) * 4) = pk;
    }
  }

  // PV: out[q, dh] += P[q, key] * V^T[dh, key]
#pragma unroll
  for (int c = 0; c < NC; ++c) {
    int cc = (NC == 2) ? c : 1;
    int prow = cc * 16 + lr;
#pragma unroll
    for (int kk = 0; kk < 2; ++kk) {
      bf16x8 pa = *(const bf16x8*)(pw + prow * 64 + (((kk * 4 + g) ^ (prow & 7)) << 3));
#pragma unroll
      for (int jf = 0; jf < 4; ++jf)
        acc[cc][jf] = mma16(pa, vb[kk][jf], acc[cc][jf]);
    }
  }
}

__global__ __launch_bounds__(256, 2) void k_attn(const short* __restrict__ q_b,
                                                 const short* __restrict__ k_b,
                                                 const short* __restrict__ vT_b,
                                                 short* __restrict__ o_b) {
  __shared__ short Ks[3][64 * 64];   // 24 KB
  __shared__ short VTs[3][64 * 64];  // 24 KB
  __shared__ short Ps[4][32 * 64];   // 16 KB
  int tid = threadIdx.x;
  int w = tid >> 6, l = tid & 63;
  int lr = l & 15, g = l >> 4;
  int ib = blockIdx.x, bh = blockIdx.y;
  int qlo = ib, qhi = 31 - ib;
  int qb0 = qlo * 64 + w * 16;  // wave q base, c=0
  int qb1 = qhi * 64 + w * 16;  // wave q base, c=1

  // Q fragments (B-operand: n-row = q = qb_c + lr, k-elems = kk*32 + g*8)
  bf16x8 qf[2][2];
  const short* Qg = q_b + (size_t)bh * 2048 * 64;
#pragma unroll
  for (int kk = 0; kk < 2; ++kk) {
    qf[0][kk] = *(const bf16x8*)(Qg + (size_t)(qb0 + lr) * 64 + kk * 32 + g * 8);
    qf[1][kk] = *(const bf16x8*)(Qg + (size_t)(qb1 + lr) * 64 + kk * 32 + g * 8);
  }

  f32x4 acc[2][4] = {};
  float mrow[2] = {-INFINITY, -INFINITY};
  float dden[2] = {0.0f, 0.0f};
  int nt = qhi + 1;  // >= 17
  const short* Kg = k_b + (size_t)bh * 2048 * 64;
  const short* Vg = vT_b + (size_t)bh * 64 * 2048;
  short* pw = &Ps[w][0];

  // prologue: stage tiles 0 and 1 (4 loads/thread each)
  stage_swz<64>(Kg, 64, &Ks[0][0], tid);
  stage_swz<64>(Vg, 2048, &VTs[0][0], tid);
  stage_swz<64>(Kg + 64 * 64, 64, &Ks[1][0], tid);
  stage_swz<64>(Vg + 64, 2048, &VTs[1][0], tid);

  // Phase A: kt in [0, qlo] -> both c-groups
#pragma unroll 1
  for (int kt = 0; kt <= qlo; ++kt) {
    VMCNT(4);  // wait tile kt's 4 loads; tile kt+1's stay in flight
    BARF();
    if (kt + 2 < nt) {
      int sl = (kt + 2) % 3;
      stage_swz<64>(Kg + (size_t)(kt + 2) * 64 * 64, 64, &Ks[sl][0], tid);
      stage_swz<64>(Vg + (kt + 2) * 64, 2048, &VTs[sl][0], tid);
    }
    int s = kt % 3;
    attn_tile<2>(&Ks[s][0], &VTs[s][0], pw, qf, acc, mrow, dden,
                 kt * 64, qb0, qb1, kt == qlo, false, lr, g);
  }
  // Phase B: kt in (qlo, qhi] -> only c=1
#pragma unroll 1
  for (int kt = qlo + 1; kt < nt; ++kt) {
    VMCNT(4);
    BARF();
    if (kt + 2 < nt) {
      int sl = (kt + 2) % 3;
      stage_swz<64>(Kg + (size_t)(kt + 2) * 64 * 64, 64, &Ks[sl][0], tid);
      stage_swz<64>(Vg + (kt + 2) * 64, 2048, &VTs[sl][0], tid);
    }
    int s = kt % 3;
    attn_tile<1>(&Ks[s][0], &VTs[s][0], pw, qf, acc, mrow, dden,
                 kt * 64, qb0, qb1, false, kt == qhi, lr, g);
  }

  // epilogue: D col = dh-within = lr, row = q-within-16 = g*4 + r
  int hh = bh & 15, b_ = bh >> 4;
#pragma unroll
  for (int c = 0; c < 2; ++c) {
    int qbc = (c == 0) ? qb0 : qb1;
#pragma unroll
    for (int r = 0; r < 4; ++r) {
      float dq = __shfl(dden[c], g * 4 + r);
      float inv = 1.0f / dq;
      int mg = qbc + g * 4 + r;
      size_t rowoff = ((size_t)b_ * 2048 + mg) * 1024 + hh * 64;
#pragma unroll
      for (int jf = 0; jf < 4; ++jf)
        o_b[rowoff + jf * 16 + lr] = f2b(acc[c][jf][r] * inv);
    }
  }
}

// ---------------------------------------------------------------------------
// Launch
// ---------------------------------------------------------------------------
extern "C" void kernel_launch(void* const* d_in, const int* in_sizes, int n_in,
                              void* d_out, int out_size, void* d_ws, size_t ws_size,
                              hipStream_t stream) {
  const float* x     = (const float*)d_in[0];
  const float* wn1   = (const float*)d_in[1];
  const float* wqkv  = (const float*)d_in[2];
  const float* wproj = (const float*)d_in[3];
  const float* wn2   = (const float*)d_in[4];
  const float* wgate = (const float*)d_in[5];
  const float* wup   = (const float*)d_in[6];
  const float* wdown = (const float*)d_in[7];
  float* out = (float*)d_out;
  char* ws = (char*)d_ws;

  short* wqkv_b  = (short*)(ws + 0);         //  6 MB
  short* wproj_b = (short*)(ws + 6291456);   //  2 MB
  short* wgate_b = (short*)(ws + 8388608);   //  8 MB
  short* wup_b   = (short*)(ws + 16777216);  //  8 MB
  short* wdown_b = (short*)(ws + 25165824);  //  8 MB
  short* h_b     = (short*)(ws + 33554432);  //  8 MB (h, then h2)
  short* q_b     = (short*)(ws + 41943040);  //  8 MB
  short* k_b     = (short*)(ws + 50331648);  //  8 MB
  short* vT_b    = (short*)(ws + 58720256);  //  8 MB
  short* ao_b    = (short*)(ws + 67108864);  //  8 MB
  short* act_b   = q_b;   // 32 MB alias over q/k/vT/ao (free after attention)
  float* x1 = out;
  float* kc = out + 4194304;
  float* vc = out + 8388608;

  k_cvt_all<<<16384, 256, 0, stream>>>(wqkv, wqkv_b, wproj, wproj_b,
                                       wgate, wgate_b, wup, wup_b, wdown, wdown_b);

  k_rms<<<4096, 256, 0, stream>>>(x, wn1, h_b);

  // qkv = h @ w_qkv^T  (grid 16x12 = 192 blocks)
  k_gemm_big<3><<<192, 512, 0, stream>>>(h_b, wqkv_b, 4096, 3072, 1024, 12,
                                         nullptr, q_b, k_b, vT_b, kc, vc);

  k_attn<<<dim3(16, 32), 256, 0, stream>>>(q_b, k_b, vT_b, ao_b);

  // x1 = x + attn @ w_proj^T  (grid 32x16 = 512 blocks)
  k_gemm_skinny<<<512, 256, 0, stream>>>(ao_b, wproj_b, 4096, 1024, 1024, 16,
                                         x, x1);

  k_rms<<<4096, 256, 0, stream>>>(x1, wn2, h_b);

  // gate = h2 @ w_gate^T (bf16)
  k_gemm_big<1><<<256, 512, 0, stream>>>(h_b, wgate_b, 4096, 4096, 1024, 16,
                                         act_b, nullptr, nullptr, nullptr, nullptr, nullptr);
  // act = silu(gate) * (h2 @ w_up^T)
  k_gemm_big<2><<<256, 512, 0, stream>>>(h_b, wup_b, 4096, 4096, 1024, 16,
                                         act_b, nullptr, nullptr, nullptr, nullptr, nullptr);
  // x_out = x1 + act @ w_down^T
  k_gemm_skinny<<<512, 256, 0, stream>>>(act_b, wdown_b, 4096, 1024, 4096, 16,
                                         x1, out);
}

// Round 7
// 337.219 us; speedup vs baseline: 1.1075x; 1.0086x over previous
//
#include <hip/hip_runtime.h>
#include <hip/hip_bf16.h>
#include <cstdint>
#include <cstddef>

// B=2, T=2048, D=1024, H=16, DH=64, CTX=2048.  M = B*T = 4096.

using bf16x8 = __attribute__((ext_vector_type(8))) __bf16;
using f32x4  = __attribute__((ext_vector_type(4))) float;

#define VMCNT(n) asm volatile("s_waitcnt vmcnt(" #n ")" ::: "memory")
#define LGKM0()  do { asm volatile("s_waitcnt lgkmcnt(0)" ::: "memory"); \
                      __builtin_amdgcn_sched_barrier(0); } while (0)
#define BARF()   do { asm volatile("" ::: "memory"); __builtin_amdgcn_s_barrier(); \
                      asm volatile("" ::: "memory"); } while (0)

__device__ __forceinline__ short f2b(float f) {
  uint32_t u = __builtin_bit_cast(uint32_t, f);
  uint32_t r = (u + 0x7FFFu + ((u >> 16) & 1u)) >> 16;
  return (short)r;
}
__device__ __forceinline__ float b2f(short s) {
  uint32_t u = ((uint32_t)(uint16_t)s) << 16;
  return __builtin_bit_cast(float, u);
}
// truncation pack of two f32 -> two bf16 in a u32 (P values in [0,1]; bias <0.4%)
__device__ __forceinline__ uint32_t pack2(float a, float b) {
  return (__builtin_bit_cast(uint32_t, a) >> 16) |
         (__builtin_bit_cast(uint32_t, b) & 0xFFFF0000u);
}

__device__ __forceinline__ void gload16(const short* g, short* l) {
  __builtin_amdgcn_global_load_lds(
      (const __attribute__((address_space(1))) void*)g,
      (__attribute__((address_space(3))) void*)l, 16, 0, 0);
}

// ---------------------------------------------------------------------------
// Staging, 64-col (128B) rows, XOR (row&7) swizzle applied on GLOBAL source,
// linear LDS dest (global_load_lds requirement).  Zero-bank-conflict verified.
// ---------------------------------------------------------------------------
template<int ROWS>  // 256 threads, ROWS/32 loads per thread
__device__ __forceinline__ void stage_swz(const short* __restrict__ g, int ldg,
                                          short* lds, int tid) {
#pragma unroll
  for (int jj = 0; jj < ROWS / 32; ++jj) {
    int row = jj * 32 + (tid >> 3);
    int seg = tid & 7;
    gload16(g + (size_t)row * ldg + ((seg ^ (row & 7)) << 3),
            lds + row * 64 + (seg << 3));
  }
}

// 512 threads, one 64-row round per call
__device__ __forceinline__ void stage_round512(const short* __restrict__ g, int ldg,
                                               short* lds, int tid, int rbase) {
  int row = rbase + (tid >> 3);
  int seg = tid & 7;
  gload16(g + (size_t)row * ldg + ((seg ^ (row & 7)) << 3),
          lds + row * 64 + (seg << 3));
}

__device__ __forceinline__ bf16x8 frag64(const short* lds, int row, int seg) {
  return *(const bf16x8*)(lds + row * 64 + ((seg ^ (row & 7)) << 3));
}

__device__ __forceinline__ f32x4 mma16(bf16x8 a, bf16x8 b, f32x4 c) {
  return __builtin_amdgcn_mfma_f32_16x16x32_bf16(a, b, c, 0, 0, 0);
}

// ---------------------------------------------------------------------------
// Fused weight conversion f32 -> bf16
// ---------------------------------------------------------------------------
__global__ void k_cvt_all(const float* __restrict__ wqkv, short* __restrict__ oqkv,
                          const float* __restrict__ wproj, short* __restrict__ oproj,
                          const float* __restrict__ wgate, short* __restrict__ ogate,
                          const float* __restrict__ wup, short* __restrict__ oup,
                          const float* __restrict__ wdown, short* __restrict__ odown) {
  int bid = blockIdx.x;
  const float* src;
  short* dst;
  int off;
  if (bid < 3072)       { src = wqkv;  dst = oqkv;  off = bid; }
  else if (bid < 4096)  { src = wproj; dst = oproj; off = bid - 3072; }
  else if (bid < 8192)  { src = wgate; dst = ogate; off = bid - 4096; }
  else if (bid < 12288) { src = wup;   dst = oup;   off = bid - 8192; }
  else                  { src = wdown; dst = odown; off = bid - 12288; }
  int i = off * 256 + threadIdx.x;
  float4 v = ((const float4*)src)[i];
  ((short4*)dst)[i] = make_short4(f2b(v.x), f2b(v.y), f2b(v.z), f2b(v.w));
}

// ---------------------------------------------------------------------------
// RMSNorm: one block (256 thr) per row of 1024 f32 -> bf16
// ---------------------------------------------------------------------------
__global__ void k_rms(const float* __restrict__ x, const float* __restrict__ w,
                      short* __restrict__ out) {
  int row = blockIdx.x;
  int tid = threadIdx.x;
  float4 v = *(const float4*)(x + (size_t)row * 1024 + tid * 4);
  float ss = v.x * v.x + v.y * v.y + v.z * v.z + v.w * v.w;
#pragma unroll
  for (int o = 1; o < 64; o <<= 1) ss += __shfl_xor(ss, o);
  __shared__ float sred[4];
  int wid = tid >> 6, lane = tid & 63;
  if (lane == 0) sred[wid] = ss;
  __syncthreads();
  float tot = sred[0] + sred[1] + sred[2] + sred[3];
  float r = rsqrtf(tot * (1.0f / 1024.0f) + 1e-6f);
  float4 wv = *(const float4*)(w + tid * 4);
  short4 o = make_short4(f2b(v.x * r * wv.x), f2b(v.y * r * wv.y),
                         f2b(v.z * r * wv.z), f2b(v.w * r * wv.w));
  *(short4*)(out + (size_t)row * 1024 + tid * 4) = o;
}

// ---------------------------------------------------------------------------
// Big GEMM v2: C = A[M,K] * W[N,K]^T, 256x256 tile, BK=64, 2-slot dbuf,
// 8 waves (2M x 4N, wave-tile 128x64).  B fragments read ONCE per iter into
// registers (frees the B slot after ph1 -> B prefetch distance ~1.75 iter,
// same as A).  3 barriers/iter, counted vmcnt(8), setprio MFMA clusters.
// MODE 1: outb = bf16(C); MODE 2: outb = bf16(silu(outb)*C); MODE 3: QKV.
// ---------------------------------------------------------------------------
template<int MODE>
__global__ __launch_bounds__(512, 2) void k_gemm_big(
    const short* __restrict__ A, const short* __restrict__ Bw,
    int M, int N, int K, int gx,
    short* __restrict__ outb,
    short* __restrict__ q_b, short* __restrict__ k_b, short* __restrict__ vT_b,
    float* __restrict__ kc, float* __restrict__ vc) {
  __shared__ short As[2][256 * 64];  // 64 KB
  __shared__ short Bs[2][256 * 64];  // 64 KB
  int tid = threadIdx.x;
  int nwg = gridDim.x, bid = blockIdx.x;
  int swz = (bid & 7) * (nwg >> 3) + (bid >> 3);
  int bx = swz % gx, by = swz / gx;
  int m0 = by * 256, n0 = bx * 256;
  int w = tid >> 6, l = tid & 63;
  int wr = w >> 2, wc = w & 3;
  int lr = l & 15, lseg = l >> 4;
  f32x4 acc[2][2][4][2] = {};
  int nk = K >> 6;
  const short* Ab = A + (size_t)m0 * K;
  const short* Bb = Bw + (size_t)n0 * K;

  // prologue: A(0), B(0), A(1), B(1) (16 loads/thread; oldest 8 = tile 0)
#pragma unroll
  for (int r = 0; r < 4; ++r) stage_round512(Ab, K, &As[0][0], tid, r * 64);
#pragma unroll
  for (int r = 0; r < 4; ++r) stage_round512(Bb, K, &Bs[0][0], tid, r * 64);
#pragma unroll
  for (int r = 0; r < 4; ++r) stage_round512(Ab + 64, K, &As[1][0], tid, r * 64);
#pragma unroll
  for (int r = 0; r < 4; ++r) stage_round512(Bb + 64, K, &Bs[1][0], tid, r * 64);

  bf16x8 ar[4][2], br[2][2][2];  // br[bh][j][kk]
#pragma unroll 1
  for (int u = 0; u < nk; ++u) {
    int s = u & 1;
    short* Asl = &As[s][0];
    short* Bsl = &Bs[s][0];
    const short* Ag2 = Ab + (u + 2) * 64;
    const short* Bg2 = Bb + (u + 2) * 64;
    bool pf = (u + 2 < nk);

    // tile u resident (8 newest in flight = tile u+1's loads)
    VMCNT(8);
    BARF();

    // ---- phase 0: read br(bh0) + ar(ah0); MFMA (ah0,bh0)
#pragma unroll
    for (int j = 0; j < 2; ++j)
#pragma unroll
      for (int kk = 0; kk < 2; ++kk)
        br[0][j][kk] = frag64(Bsl, wc * 64 + j * 16 + lr, kk * 4 + lseg);
#pragma unroll
    for (int i = 0; i < 4; ++i)
#pragma unroll
      for (int kk = 0; kk < 2; ++kk)
        ar[i][kk] = frag64(Asl, wr * 128 + i * 16 + lr, kk * 4 + lseg);
    LGKM0();
    __builtin_amdgcn_s_setprio(1);
#pragma unroll
    for (int i = 0; i < 4; ++i)
#pragma unroll
      for (int j = 0; j < 2; ++j) {
        acc[0][0][i][j] = mma16(ar[i][0], br[0][j][0], acc[0][0][i][j]);
        acc[0][0][i][j] = mma16(ar[i][1], br[0][j][1], acc[0][0][i][j]);
      }
    __builtin_amdgcn_s_setprio(0);

    // ---- phase 1: read br(bh1); MFMA (ah0,bh1)
#pragma unroll
    for (int j = 0; j < 2; ++j)
#pragma unroll
      for (int kk = 0; kk < 2; ++kk)
        br[1][j][kk] = frag64(Bsl, wc * 64 + 32 + j * 16 + lr, kk * 4 + lseg);
    LGKM0();
    __builtin_amdgcn_s_setprio(1);
#pragma unroll
    for (int i = 0; i < 4; ++i)
#pragma unroll
      for (int j = 0; j < 2; ++j) {
        acc[0][1][i][j] = mma16(ar[i][0], br[1][j][0], acc[0][1][i][j]);
        acc[0][1][i][j] = mma16(ar[i][1], br[1][j][1], acc[0][1][i][j]);
      }
    __builtin_amdgcn_s_setprio(0);
    BARF();  // all waves done reading B slot + ah0 rows

    // stage B(u+2) -> current B slot; A(u+2) ah0 rows -> current A slot
    if (pf) {
#pragma unroll
      for (int r = 0; r < 4; ++r) stage_round512(Bg2, K, Bsl, tid, r * 64);
      stage_round512(Ag2, K, Asl, tid, 0);
      stage_round512(Ag2, K, Asl, tid, 128);
    }

    // ---- phase 2: read ar(ah1); MFMA (ah1,bh0)
#pragma unroll
    for (int i = 0; i < 4; ++i)
#pragma unroll
      for (int kk = 0; kk < 2; ++kk)
        ar[i][kk] = frag64(Asl, wr * 128 + 64 + i * 16 + lr, kk * 4 + lseg);
    LGKM0();
    __builtin_amdgcn_s_setprio(1);
#pragma unroll
    for (int i = 0; i < 4; ++i)
#pragma unroll
      for (int j = 0; j < 2; ++j) {
        acc[1][0][i][j] = mma16(ar[i][0], br[0][j][0], acc[1][0][i][j]);
        acc[1][0][i][j] = mma16(ar[i][1], br[0][j][1], acc[1][0][i][j]);
      }
    __builtin_amdgcn_s_setprio(0);
    BARF();  // all waves done reading ah1 rows

    // stage A(u+2) ah1 rows
    if (pf) {
      stage_round512(Ag2, K, Asl, tid, 64);
      stage_round512(Ag2, K, Asl, tid, 192);
    }

    // ---- phase 3: MFMA (ah1,bh1) — pure register phase
    __builtin_amdgcn_s_setprio(1);
#pragma unroll
    for (int i = 0; i < 4; ++i)
#pragma unroll
      for (int j = 0; j < 2; ++j) {
        acc[1][1][i][j] = mma16(ar[i][0], br[1][j][0], acc[1][1][i][j]);
        acc[1][1][i][j] = mma16(ar[i][1], br[1][j][1], acc[1][1][i][j]);
      }
    __builtin_amdgcn_s_setprio(0);
  }

  // epilogue: C frag col = l&15, row = (l>>4)*4 + r
#pragma unroll
  for (int ah = 0; ah < 2; ++ah) {
#pragma unroll
    for (int bh = 0; bh < 2; ++bh) {
#pragma unroll
      for (int i = 0; i < 4; ++i) {
#pragma unroll
        for (int j = 0; j < 2; ++j) {
#pragma unroll
          for (int r = 0; r < 4; ++r) {
            int m = m0 + wr * 128 + ah * 64 + i * 16 + (l >> 4) * 4 + r;
            int n = n0 + wc * 64 + bh * 32 + j * 16 + lr;
            float f = acc[ah][bh][i][j][r];
            if (MODE == 1) {
              outb[(size_t)m * N + n] = f2b(f);
            } else if (MODE == 2) {
              float g = b2f(outb[(size_t)m * N + n]);
              float sg = g / (1.0f + __expf(-g));
              outb[(size_t)m * N + n] = f2b(sg * f);
            } else {
              int jj = n >> 10, hh = (n >> 6) & 15, dh = n & 63;
              int b_ = m >> 11, t = m & 2047;
              int bhh = b_ * 16 + hh;
              size_t idx = ((size_t)bhh * 2048 + t) * 64 + dh;
              if (jj == 0) {
                q_b[idx] = f2b(f);
              } else if (jj == 1) {
                k_b[idx] = f2b(f);
                kc[idx] = f;
              } else {
                vT_b[((size_t)bhh * 64 + dh) * 2048 + t] = f2b(f);
                vc[idx] = f;
              }
            }
          }
        }
      }
    }
  }
}

// ---------------------------------------------------------------------------
// Skinny GEMM: 128x64 tile, BK=64, ring-3, 4 waves (2M x 2N, wave 64x32).
// outf[m,n] = C + res[m,n]   (proj, down; N=1024 -> grid 32x16=512, 2 blk/CU)
// ---------------------------------------------------------------------------
__global__ __launch_bounds__(256, 2) void k_gemm_skinny(
    const short* __restrict__ A, const short* __restrict__ Bw,
    int M, int N, int K, int gx,
    const float* __restrict__ res, float* __restrict__ outf) {
  __shared__ short As[3][128 * 64];  // 48 KB
  __shared__ short Bs[3][64 * 64];   // 24 KB
  int tid = threadIdx.x;
  int nwg = gridDim.x, bid = blockIdx.x;
  int swz = (bid & 7) * (nwg >> 3) + (bid >> 3);
  int bx = swz % gx, by = swz / gx;
  int m0 = by * 128, n0 = bx * 64;
  int w = tid >> 6, l = tid & 63;
  int wr = w >> 1, wc = w & 1;
  int lr = l & 15, lseg = l >> 4;
  f32x4 acc[4][2] = {};
  int nk = K >> 6;
  const short* Ab = A + (size_t)m0 * K;
  const short* Bb = Bw + (size_t)n0 * K;

  stage_swz<128>(Ab, K, &As[0][0], tid);
  stage_swz<64>(Bb, K, &Bs[0][0], tid);
  stage_swz<128>(Ab + 64, K, &As[1][0], tid);
  stage_swz<64>(Bb + 64, K, &Bs[1][0], tid);

#pragma unroll 1
  for (int u = 0; u < nk; ++u) {
    VMCNT(6);   // tiles u+1, u+2 may stay in flight (6 loads/tile)
    BARF();
    if (u + 2 < nk) {
      int sl = (u + 2) % 3;
      stage_swz<128>(Ab + (u + 2) * 64, K, &As[sl][0], tid);
      stage_swz<64>(Bb + (u + 2) * 64, K, &Bs[sl][0], tid);
    }
    const short* Asl = &As[u % 3][0];
    const short* Bsl = &Bs[u % 3][0];
    bf16x8 ar[4][2], br[2][2];
#pragma unroll
    for (int i = 0; i < 4; ++i)
#pragma unroll
      for (int kk = 0; kk < 2; ++kk)
        ar[i][kk] = frag64(Asl, wr * 64 + i * 16 + lr, kk * 4 + lseg);
#pragma unroll
    for (int j = 0; j < 2; ++j)
#pragma unroll
      for (int kk = 0; kk < 2; ++kk)
        br[j][kk] = frag64(Bsl, wc * 32 + j * 16 + lr, kk * 4 + lseg);
    LGKM0();
    __builtin_amdgcn_s_setprio(1);
#pragma unroll
    for (int i = 0; i < 4; ++i)
#pragma unroll
      for (int j = 0; j < 2; ++j) {
        acc[i][j] = mma16(ar[i][0], br[j][0], acc[i][j]);
        acc[i][j] = mma16(ar[i][1], br[j][1], acc[i][j]);
      }
    __builtin_amdgcn_s_setprio(0);
  }

#pragma unroll
  for (int i = 0; i < 4; ++i) {
#pragma unroll
    for (int j = 0; j < 2; ++j) {
#pragma unroll
      for (int r = 0; r < 4; ++r) {
        int m = m0 + wr * 64 + i * 16 + (l >> 4) * 4 + r;
        int n = n0 + wc * 32 + j * 16 + lr;
        outf[(size_t)m * N + n] = acc[i][j][r] + res[(size_t)m * N + n];
      }
    }
  }
}

// ---------------------------------------------------------------------------
// Causal flash attention v4 — balanced pairing + ring-3 counted-vmcnt
// prefetch + interleaved c-groups via phase-split loops.
// ---------------------------------------------------------------------------
template<int NC>
__device__ __forceinline__ void attn_tile(
    const short* __restrict__ Ksl, const short* __restrict__ Vsl,
    short* __restrict__ pw,
    const bf16x8 (&qf)[2][2], f32x4 (&acc)[2][4],
    float (&mrow)[2], float (&dden)[2],
    int kv0, int qb0, int qb1, bool band0, bool band1,
    int lr, int g) {
  // hoisted K and V fragments (shared across c-groups)
  bf16x8 kf[4][2], vb[2][4];
#pragma unroll
  for (int i = 0; i < 4; ++i)
#pragma unroll
    for (int kk = 0; kk < 2; ++kk)
      kf[i][kk] = frag64(Ksl, i * 16 + lr, kk * 4 + g);
#pragma unroll
  for (int kk = 0; kk < 2; ++kk)
#pragma unroll
    for (int jf = 0; jf < 4; ++jf)
      vb[kk][jf] = frag64(Vsl, jf * 16 + lr, kk * 4 + g);

  // QK^T for all active c-groups (independent MFMAs -> ILP)
  f32x4 st[NC][4];
#pragma unroll
  for (int c = 0; c < NC; ++c) {
    int cc = (NC == 2) ? c : 1;
#pragma unroll
    for (int i = 0; i < 4; ++i) {
      f32x4 z = {};
      z = mma16(kf[i][0], qf[cc][0], z);
      z = mma16(kf[i][1], qf[cc][1], z);
      st[c][i] = z;
    }
  }

  // online softmax in exp2 domain, both chains interleaved
  const float SC = 0.125f * 1.44269504f;
  float p[NC][16], pm[NC], corr[NC];
#pragma unroll
  for (int c = 0; c < NC; ++c) {
    int cc = (NC == 2) ? c : 1;
    bool band = (cc == 0) ? band0 : band1;
    int qgc = ((cc == 0) ? qb0 : qb1) + lr;
    float m_ = -INFINITY;
#pragma unroll
    for (int i = 0; i < 4; ++i)
#pragma unroll
      for (int r = 0; r < 4; ++r) {
        float v = st[c][i][r] * SC;
        if (band) {
          int key = kv0 + i * 16 + g * 4 + r;
          if (key > qgc) v = -INFINITY;
        }
        p[c][i * 4 + r] = v;
        m_ = fmaxf(m_, v);
      }
    pm[c] = m_;
  }
#pragma unroll
  for (int c = 0; c < NC; ++c) pm[c] = fmaxf(pm[c], __shfl_xor(pm[c], 16));
#pragma unroll
  for (int c = 0; c < NC; ++c) pm[c] = fmaxf(pm[c], __shfl_xor(pm[c], 32));
  float dsum[NC];
#pragma unroll
  for (int c = 0; c < NC; ++c) {
    int cc = (NC == 2) ? c : 1;
    float nm = fmaxf(mrow[cc], pm[c]);
    corr[c] = exp2f(mrow[cc] - nm);
    mrow[cc] = nm;
    float ds_ = 0.0f;
#pragma unroll
    for (int kx = 0; kx < 16; ++kx) {
      float pv = exp2f(p[c][kx] - nm);
      p[c][kx] = pv;
      ds_ += pv;
    }
    dsum[c] = ds_;
  }
#pragma unroll
  for (int c = 0; c < NC; ++c) dsum[c] += __shfl_xor(dsum[c], 16);
#pragma unroll
  for (int c = 0; c < NC; ++c) dsum[c] += __shfl_xor(dsum[c], 32);
#pragma unroll
  for (int c = 0; c < NC; ++c) {
    int cc = (NC == 2) ? c : 1;
    dden[cc] = dden[cc] * corr[c] + dsum[c];
  }

  // rescale acc + write P to swizzled per-wave LDS
#pragma unroll
  for (int c = 0; c < NC; ++c) {
    int cc = (NC == 2) ? c : 1;
#pragma unroll
    for (int r = 0; r < 4; ++r) {
      float cr = __shfl(corr[c], g * 4 + r);
#pragma unroll
      for (int jf = 0; jf < 4; ++jf) acc[cc][jf][r] *= cr;
    }
    int prow = cc * 16 + lr;
#pragma unroll
    for (int i = 0; i < 4; ++i) {
      uint2 pk;
      pk.x = pack2(p[c][i * 4 + 0], p[c][i * 4 + 1]);
      pk.y = pack2(p[c][i * 4 + 2], p[c][i * 4 + 3]);
      int seg = (i * 2 + (g >> 1)) ^ (prow & 7);
      *(uint2*)(pw + prow * 64 + seg * 8 + (g & 1) * 4) = pk;
    }
  }

  // PV: out[q, dh] += P[q, key] * V^T[dh, key]
#pragma unroll
  for (int c = 0; c < NC; ++c) {
    int cc = (NC == 2) ? c : 1;
    int prow = cc * 16 + lr;
#pragma unroll
    for (int kk = 0; kk < 2; ++kk) {
      bf16x8 pa = *(const bf16x8*)(pw + prow * 64 + (((kk * 4 + g) ^ (prow & 7)) << 3));
#pragma unroll
      for (int jf = 0; jf < 4; ++jf)
        acc[cc][jf] = mma16(pa, vb[kk][jf], acc[cc][jf]);
    }
  }
}

__global__ __launch_bounds__(256, 2) void k_attn(const short* __restrict__ q_b,
                                                 const short* __restrict__ k_b,
                                                 const short* __restrict__ vT_b,
                                                 short* __restrict__ o_b) {
  __shared__ short Ks[3][64 * 64];   // 24 KB
  __shared__ short VTs[3][64 * 64];  // 24 KB
  __shared__ short Ps[4][32 * 64];   // 16 KB
  int tid = threadIdx.x;
  int w = tid >> 6, l = tid & 63;
  int lr = l & 15, g = l >> 4;
  int ib = blockIdx.x, bh = blockIdx.y;
  int qlo = ib, qhi = 31 - ib;
  int qb0 = qlo * 64 + w * 16;  // wave q base, c=0
  int qb1 = qhi * 64 + w * 16;  // wave q base, c=1

  // Q fragments (B-operand: n-row = q = qb_c + lr, k-elems = kk*32 + g*8)
  bf16x8 qf[2][2];
  const short* Qg = q_b + (size_t)bh * 2048 * 64;
#pragma unroll
  for (int kk = 0; kk < 2; ++kk) {
    qf[0][kk] = *(const bf16x8*)(Qg + (size_t)(qb0 + lr) * 64 + kk * 32 + g * 8);
    qf[1][kk] = *(const bf16x8*)(Qg + (size_t)(qb1 + lr) * 64 + kk * 32 + g * 8);
  }

  f32x4 acc[2][4] = {};
  float mrow[2] = {-INFINITY, -INFINITY};
  float dden[2] = {0.0f, 0.0f};
  int nt = qhi + 1;  // >= 17
  const short* Kg = k_b + (size_t)bh * 2048 * 64;
  const short* Vg = vT_b + (size_t)bh * 64 * 2048;
  short* pw = &Ps[w][0];

  // prologue: stage tiles 0 and 1 (4 loads/thread each)
  stage_swz<64>(Kg, 64, &Ks[0][0], tid);
  stage_swz<64>(Vg, 2048, &VTs[0][0], tid);
  stage_swz<64>(Kg + 64 * 64, 64, &Ks[1][0], tid);
  stage_swz<64>(Vg + 64, 2048, &VTs[1][0], tid);

  // Phase A: kt in [0, qlo] -> both c-groups
#pragma unroll 1
  for (int kt = 0; kt <= qlo; ++kt) {
    VMCNT(4);  // wait tile kt's 4 loads; tile kt+1's stay in flight
    BARF();
    if (kt + 2 < nt) {
      int sl = (kt + 2) % 3;
      stage_swz<64>(Kg + (size_t)(kt + 2) * 64 * 64, 64, &Ks[sl][0], tid);
      stage_swz<64>(Vg + (kt + 2) * 64, 2048, &VTs[sl][0], tid);
    }
    int s = kt % 3;
    attn_tile<2>(&Ks[s][0], &VTs[s][0], pw, qf, acc, mrow, dden,
                 kt * 64, qb0, qb1, kt == qlo, false, lr, g);
  }
  // Phase B: kt in (qlo, qhi] -> only c=1
#pragma unroll 1
  for (int kt = qlo + 1; kt < nt; ++kt) {
    VMCNT(4);
    BARF();
    if (kt + 2 < nt) {
      int sl = (kt + 2) % 3;
      stage_swz<64>(Kg + (size_t)(kt + 2) * 64 * 64, 64, &Ks[sl][0], tid);
      stage_swz<64>(Vg + (kt + 2) * 64, 2048, &VTs[sl][0], tid);
    }
    int s = kt % 3;
    attn_tile<1>(&Ks[s][0], &VTs[s][0], pw, qf, acc, mrow, dden,
                 kt * 64, qb0, qb1, false, kt == qhi, lr, g);
  }

  // epilogue: D col = dh-within = lr, row = q-within-16 = g*4 + r
  int hh = bh & 15, b_ = bh >> 4;
#pragma unroll
  for (int c = 0; c < 2; ++c) {
    int qbc = (c == 0) ? qb0 : qb1;
#pragma unroll
    for (int r = 0; r < 4; ++r) {
      float dq = __shfl(dden[c], g * 4 + r);
      float inv = 1.0f / dq;
      int mg = qbc + g * 4 + r;
      size_t rowoff = ((size_t)b_ * 2048 + mg) * 1024 + hh * 64;
#pragma unroll
      for (int jf = 0; jf < 4; ++jf)
        o_b[rowoff + jf * 16 + lr] = f2b(acc[c][jf][r] * inv);
    }
  }
}

// ---------------------------------------------------------------------------
// Launch
// ---------------------------------------------------------------------------
extern "C" void kernel_launch(void* const* d_in, const int* in_sizes, int n_in,
                              void* d_out, int out_size, void* d_ws, size_t ws_size,
                              hipStream_t stream) {
  const float* x     = (const float*)d_in[0];
  const float* wn1   = (const float*)d_in[1];
  const float* wqkv  = (const float*)d_in[2];
  const float* wproj = (const float*)d_in[3];
  const float* wn2   = (const float*)d_in[4];
  const float* wgate = (const float*)d_in[5];
  const float* wup   = (const float*)d_in[6];
  const float* wdown = (const float*)d_in[7];
  float* out = (float*)d_out;
  char* ws = (char*)d_ws;

  short* wqkv_b  = (short*)(ws + 0);         //  6 MB
  short* wproj_b = (short*)(ws + 6291456);   //  2 MB
  short* wgate_b = (short*)(ws + 8388608);   //  8 MB
  short* wup_b   = (short*)(ws + 16777216);  //  8 MB
  short* wdown_b = (short*)(ws + 25165824);  //  8 MB
  short* h_b     = (short*)(ws + 33554432);  //  8 MB (h, then h2)
  short* q_b     = (short*)(ws + 41943040);  //  8 MB
  short* k_b     = (short*)(ws + 50331648);  //  8 MB
  short* vT_b    = (short*)(ws + 58720256);  //  8 MB
  short* ao_b    = (short*)(ws + 67108864);  //  8 MB
  short* act_b   = q_b;   // 32 MB alias over q/k/vT/ao (free after attention)
  float* x1 = out;
  float* kc = out + 4194304;
  float* vc = out + 8388608;

  k_cvt_all<<<16384, 256, 0, stream>>>(wqkv, wqkv_b, wproj, wproj_b,
                                       wgate, wgate_b, wup, wup_b, wdown, wdown_b);

  k_rms<<<4096, 256, 0, stream>>>(x, wn1, h_b);

  // qkv = h @ w_qkv^T  (grid 16x12 = 192 blocks)
  k_gemm_big<3><<<192, 512, 0, stream>>>(h_b, wqkv_b, 4096, 3072, 1024, 12,
                                         nullptr, q_b, k_b, vT_b, kc, vc);

  k_attn<<<dim3(16, 32), 256, 0, stream>>>(q_b, k_b, vT_b, ao_b);

  // x1 = x + attn @ w_proj^T  (grid 32x16 = 512 blocks)
  k_gemm_skinny<<<512, 256, 0, stream>>>(ao_b, wproj_b, 4096, 1024, 1024, 16,
                                         x, x1);

  k_rms<<<4096, 256, 0, stream>>>(x1, wn2, h_b);

  // gate = h2 @ w_gate^T (bf16)
  k_gemm_big<1><<<256, 512, 0, stream>>>(h_b, wgate_b, 4096, 4096, 1024, 16,
                                         act_b, nullptr, nullptr, nullptr, nullptr, nullptr);
  // act = silu(gate) * (h2 @ w_up^T)
  k_gemm_big<2><<<256, 512, 0, stream>>>(h_b, wup_b, 4096, 4096, 1024, 16,
                                         act_b, nullptr, nullptr, nullptr, nullptr, nullptr);
  // x_out = x1 + act @ w_down^T
  k_gemm_skinny<<<512, 256, 0, stream>>>(act_b, wdown_b, 4096, 1024, 4096, 16,
                                         x1, out);
}